// Round 9
// baseline (597.518 us; speedup 1.0000x reference)
//
#include <hip/hip_runtime.h>

#define NN     50000
#define NE     200000
#define ETOT   250000   // NE + NN self-loops
#define FIN    165
#define KP1    192      // FIN padded to 3*64 K-tiles
#define HEADS  8
#define CH     100
#define DIM    800      // 8*100
#define MPAD   50176    // 196*256
#define NP1    1024     // 4*256  (pad of 816: 800 data + 16 es/ed)
#define DIM2   1600     // W2|Wres1 fused output
#define KP2    832      // 800 padded to 13*64 K-tiles
#define NP2    1792     // 7*256  (pad of 1616: 1600 data + 16 es/ed)
#define NEG    0.2f

typedef unsigned short u16;
typedef unsigned int   u32;
typedef __bf16 bf16x8 __attribute__((ext_vector_type(8)));
typedef float  f32x4  __attribute__((ext_vector_type(4)));

__device__ __forceinline__ u16 f2b(float f) {
  u32 u = __float_as_uint(f);
  u = (u + 0x7FFFu + ((u >> 16) & 1u)) >> 16;   // RNE
  return (u16)u;
}
__device__ __forceinline__ float b2f(u16 u) { return __uint_as_float(((u32)u) << 16); }

// ---------------- CSR build (dst -> list of src), reused by all 3 layers ----------------
__global__ void k_count(const int* __restrict__ ei, int* __restrict__ cnt) {
  int e = blockIdx.x * 256 + threadIdx.x;
  if (e >= ETOT) return;
  int d = (e < NE) ? ei[NE + e] : (e - NE);
  atomicAdd(&cnt[d], 1);
}
__global__ void k_bsum(const int* __restrict__ cnt, int* __restrict__ bs) {
  __shared__ int sm[256];
  int i = blockIdx.x * 256 + threadIdx.x;
  sm[threadIdx.x] = (i < NN) ? cnt[i] : 0;
  __syncthreads();
  for (int off = 128; off; off >>= 1) {
    if (threadIdx.x < off) sm[threadIdx.x] += sm[threadIdx.x + off];
    __syncthreads();
  }
  if (!threadIdx.x) bs[blockIdx.x] = sm[0];
}
__global__ void k_top(int* __restrict__ bs, int* __restrict__ rs, int nb) {
  __shared__ int sm[256];
  int t = threadIdx.x;
  int v = (t < nb) ? bs[t] : 0;
  sm[t] = v; __syncthreads();
  for (int off = 1; off < 256; off <<= 1) {
    int add = (t >= off) ? sm[t - off] : 0;
    __syncthreads();
    sm[t] += add;
    __syncthreads();
  }
  if (t < nb) bs[t] = sm[t] - v;   // exclusive block offsets
  if (!t) rs[NN] = ETOT;
}
__global__ void k_scan(const int* __restrict__ cnt, const int* __restrict__ bs, int* __restrict__ rs) {
  __shared__ int sm[256];
  int t = threadIdx.x, i = blockIdx.x * 256 + t;
  int v = (i < NN) ? cnt[i] : 0;
  sm[t] = v; __syncthreads();
  for (int off = 1; off < 256; off <<= 1) {
    int add = (t >= off) ? sm[t - off] : 0;
    __syncthreads();
    sm[t] += add;
    __syncthreads();
  }
  if (i < NN) rs[i] = bs[blockIdx.x] + sm[t] - v;
}
__global__ void k_fill(const int* __restrict__ ei, const int* __restrict__ rs,
                       int* __restrict__ cur, int* __restrict__ esrc) {
  int e = blockIdx.x * 256 + threadIdx.x;
  if (e >= ETOT) return;
  int s, d;
  if (e < NE) { s = ei[e]; d = ei[NE + e]; } else { s = d = e - NE; }
  int pos = atomicAdd(&cur[d], 1);
  esrc[rs[d] + pos] = s;
}

// ---------------- converts (fp32 -> bf16, pad, transpose weights) ----------------
__global__ void k_cvt_x(const float* __restrict__ x, u16* __restrict__ A) {
  int idx = blockIdx.x * 256 + threadIdx.x;   // MPAD*KP1 exact
  int r = idx / KP1, k = idx - r * KP1;
  float v = (r < NN && k < FIN) ? x[r * FIN + k] : 0.f;
  A[idx] = f2b(v);
}
__global__ void k_cvt_w1(const float* __restrict__ W1, u16* __restrict__ Bt) {
  int idx = blockIdx.x * 256 + threadIdx.x;   // DIM*KP1 exact
  if (idx >= DIM * KP1) return;
  int j = idx / KP1, k = idx - j * KP1;
  float v = (k < FIN) ? W1[k * DIM + j] : 0.f;
  Bt[idx] = f2b(v);
}
__global__ void k_cvt_w2(const float* __restrict__ W2, const float* __restrict__ Wr1,
                         u16* __restrict__ Bt) {
  int idx = blockIdx.x * 256 + threadIdx.x;   // DIM2*KP2 exact
  if (idx >= DIM2 * KP2) return;
  int j = idx / KP2, k = idx - j * KP2;
  float v = 0.f;
  if (k < DIM) v = (j < DIM) ? W2[k * DIM + j] : Wr1[k * DIM + (j - DIM)];
  Bt[idx] = f2b(v);
}
// fused attention columns: Wt row (Dsp+j), j=h -> (W @ a_src blockdiag), j=8+h -> a_dst.
__global__ void k_wa(const float* __restrict__ W, const float* __restrict__ as,
                     const float* __restrict__ ad, u16* __restrict__ Wt,
                     int Kin, int Kpad, int Dsp) {
  int idx = blockIdx.x * 256 + threadIdx.x;
  if (idx >= 16 * Kpad) return;
  int j = idx / Kpad, k = idx - j * Kpad;
  int h = j & 7;
  const float* a = ((j < 8) ? as : ad) + h * CH;
  float s = 0.f;
  if (k < Kin) {
    const float* wr = W + (size_t)k * DIM + h * CH;
    for (int c = 0; c < CH; ++c) s += wr[c] * a[c];
  }
  Wt[(size_t)(Dsp + j) * Kpad + k] = f2b(s);
}

// ------------- 256x256 MFMA GEMM, BK=64, 8 waves, T1+T2+T5, minimal-barrier -------------
// R7/R8 addressing & T2 layout kept bit-identical (0 bank conflicts verified).
// Schedule changes vs R8 (both attack the measured ~7000cyc/K-tile vs 2480 MFMA-min):
//  (1) kk OUTERMOST in the MFMA cluster: 8 independent MFMAs between reuses of the
//      same accumulator (R8 issued dependent pairs back-to-back -> latency-bound).
//  (2) ONE barrier + one per-wave vmcnt drain per K-tile (R8 had 8 barriers):
//      issue stage(t+2) right after the barrier, compute tile t with NO internal
//      barriers (compiler's counted lgkmcnt interleaves ds_read/MFMA), then
//      WAITVM(0) (drains stage(t+1), in flight one full tile) ; BARRIER (publishes
//      buf[1-p] to all waves + proves all waves done reading buf p => WAR-safe
//      for next issue into buf p).
__device__ __forceinline__ void gl_lds16(const u16* g, u16* l) {
  __builtin_amdgcn_global_load_lds((const __attribute__((address_space(1))) void*)g,
                                   (__attribute__((address_space(3))) void*)l, 16, 0, 0);
}
#define WAITVM(N) asm volatile("s_waitcnt vmcnt(" #N ")" ::: "memory")
#define BARRIER() asm volatile("s_barrier" ::: "memory")

__global__ __launch_bounds__(512, 2) void k_gemm256(
    const u16* __restrict__ A, const u16* __restrict__ Bt, u16* __restrict__ C,
    float* __restrict__ es, float* __restrict__ ed,
    int Kpad, int NT, int Dsplit, int Nreal, int ldC, int Mreal) {
  __shared__ __align__(16) u16 lA[2][16384];
  __shared__ __align__(16) u16 lB[2][16384];
  const int t = threadIdx.x;
  const int lane = t & 63, w = t >> 6;
  const int wm = w >> 2, wn = w & 3;

  // T1 XCD swizzle (bijective chunked, m204)
  int nwg = gridDim.x * gridDim.y;
  int hid = blockIdx.y * gridDim.x + blockIdx.x;
  int q = nwg >> 3, r8 = nwg & 7;
  int xcd = hid & 7, i8 = hid >> 3;
  int ln = (xcd < r8 ? xcd * (q + 1) : r8 * (q + 1) + (xcd - r8) * q) + i8;
  int tn = (ln % gridDim.x) * 256, tm = (ln / gridDim.x) * 256;

  // staging source address = inverse of the subtiled+XOR LDS layout (R7-proven)
  const int srow = ((w >> 1) << 4) + (lane >> 2);                       // 0..63
  const int scol = ((w & 1) << 5) + (((lane & 3) * 8) ^ (((lane >> 5) & 1) << 4));
  const size_t rA = (size_t)(tm + srow) * Kpad + scol;
  const size_t rB = (size_t)(tn + srow) * Kpad + scol;
  const size_t oR = (size_t)64 * Kpad;
  const int dul = w * 512 + lane * 8;   // LDS dest u16 offset, linear

  f32x4 acc[8][4];
#pragma unroll
  for (int i = 0; i < 8; ++i)
#pragma unroll
    for (int j = 0; j < 4; ++j) acc[i][j] = (f32x4){0.f, 0.f, 0.f, 0.f};

  auto issue = [&](int buf, int kt) {
    const u16* pa = A + rA + (size_t)kt * 64;
    gl_lds16(pa,          &lA[buf][dul]);
    gl_lds16(pa + oR,     &lA[buf][4096 + dul]);
    gl_lds16(pa + 2 * oR, &lA[buf][8192 + dul]);
    gl_lds16(pa + 3 * oR, &lA[buf][12288 + dul]);
    const u16* pb = Bt + rB + (size_t)kt * 64;
    gl_lds16(pb,          &lB[buf][dul]);
    gl_lds16(pb + oR,     &lB[buf][4096 + dul]);
    gl_lds16(pb + 2 * oR, &lB[buf][8192 + dul]);
    gl_lds16(pb + 3 * oR, &lB[buf][12288 + dul]);
  };

  const int rl = lane & 15, kl = (lane >> 4) * 8;
  const int rdoff = rl * 32 + (kl ^ (((rl >> 3) & 1) << 4));

  issue(0, 0);
  WAITVM(0);
  BARRIER();                      // buf0 published
  if (NT > 1) issue(1, 1);        // flies during tile 0

  for (int kt = 0; kt < NT; ++kt) {
    const int p = kt & 1;
    const u16* baseA = &lA[p][wm * 8192];
    const u16* baseB = &lB[p][(wn >> 1) * 8192];
    bf16x8 b[4][2];
#pragma unroll
    for (int fc = 0; fc < 4; ++fc)
#pragma unroll
      for (int kk = 0; kk < 2; ++kk)
        b[fc][kk] = *(const bf16x8*)&baseB[((((wn & 1) * 4 + fc) * 2 + kk) << 9) + rdoff];
#pragma unroll
    for (int qm = 0; qm < 4; ++qm) {          // 2 output rows per group
      bf16x8 a2[2][2];
#pragma unroll
      for (int i = 0; i < 2; ++i)
#pragma unroll
        for (int kk = 0; kk < 2; ++kk)
          a2[i][kk] = *(const bf16x8*)&baseA[((((qm * 2 + i) * 2) + kk) << 9) + rdoff];
      __builtin_amdgcn_s_setprio(1);
#pragma unroll
      for (int kk = 0; kk < 2; ++kk)           // kk OUTER: 8 indep MFMAs per kk
#pragma unroll
        for (int i = 0; i < 2; ++i)
#pragma unroll
          for (int fc = 0; fc < 4; ++fc)
            acc[qm * 2 + i][fc] =
                __builtin_amdgcn_mfma_f32_16x16x32_bf16(a2[i][kk], b[fc][kk], acc[qm * 2 + i][fc], 0, 0, 0);
      __builtin_amdgcn_s_setprio(0);
    }
    if (kt + 1 < NT) {
      WAITVM(0);                  // drains stage(kt+1) (in flight one full tile)
      BARRIER();                  // publish buf[1-p]; WAR: all waves done with buf p
      if (kt + 2 < NT) issue(p, kt + 2);
    }
  }

  const int rq = (lane >> 4) * 4;
#pragma unroll
  for (int fr = 0; fr < 8; ++fr) {
#pragma unroll
    for (int fc = 0; fc < 4; ++fc) {
      int col = tn + wn * 64 + fc * 16 + rl;
      if (col < Dsplit) {
#pragma unroll
        for (int q2 = 0; q2 < 4; ++q2) {
          int row = tm + wm * 128 + fr * 16 + rq + q2;
          if (row < Mreal) C[(size_t)row * ldC + col] = f2b(acc[fr][fc][q2]);
        }
      } else if (col < Nreal) {
        int cj = col - Dsplit;
        float* dst = (cj < 8) ? es : ed;
        int hh = cj & 7;
#pragma unroll
        for (int q2 = 0; q2 < 4; ++q2) {
          int row = tm + wm * 128 + fr * 16 + rq + q2;
          if (row < Mreal) dst[(size_t)row * 8 + hh] = acc[fr][fc][q2];
        }
      }
    }
  }
}

// ---- per-(node,head) softmax stats; single pass (shift-invariant, m=0), stores exp ----
__global__ void k_stats(const int* __restrict__ rs, const int* __restrict__ esrc,
                        const float* __restrict__ es, const float* __restrict__ ed,
                        float* __restrict__ ex, float* __restrict__ dv) {
  int idx = blockIdx.x * 256 + threadIdx.x;
  if (idx >= NN * HEADS) return;
  int n = idx >> 3, h = idx & 7;
  int beg = rs[n], end = rs[n + 1];
  float edv = ed[idx];
  float den = 0.f;
  for (int j = beg; j < end; ++j) {
    float x = es[esrc[j] * 8 + h] + edv;
    x = x > 0.f ? x : NEG * x;
    float e = __expf(x);
    ex[j * 8 + h] = e;
    den += e;
  }
  dv[idx] = 1.f / (den + 1e-16f);
}

// ---- aggregation: 2-deep software pipeline (next edge's w+row issued before
//      current edge's FMAs) to break the gather latency chain ----
template <int LAYER>
__global__ __launch_bounds__(256) void k_agg(const int* __restrict__ rs, const int* __restrict__ esrc,
    const u16* __restrict__ Hp, const float* __restrict__ ex, const float* __restrict__ dv,
    const float* __restrict__ bias, const u16* __restrict__ resid, u16* __restrict__ out) {
  const int ld  = (LAYER == 2) ? DIM2 : DIM;
  const int old = (LAYER == 1) ? KP2 : DIM;
  int n = blockIdx.x, t = threadIdx.x;
  if (t >= 200) return;
  int beg = rs[n], end = rs[n + 1];
  int c = t * 4;
  int h = t / 25;
  float inv = dv[n * 8 + h];
  float a0 = 0.f, a1 = 0.f, a2 = 0.f, a3 = 0.f;
  float w0 = 0.f;
  ushort4 u0 = (ushort4){0, 0, 0, 0};
  if (beg < end) {
    w0 = ex[beg * 8 + h];
    u0 = *(const ushort4*)(Hp + (size_t)esrc[beg] * ld + c);
  }
  for (int j = beg; j < end; ++j) {
    float w1 = 0.f;
    ushort4 u1 = u0;
    if (j + 1 < end) {
      w1 = ex[(j + 1) * 8 + h];
      u1 = *(const ushort4*)(Hp + (size_t)esrc[j + 1] * ld + c);
    }
    a0 += w0 * b2f(u0.x); a1 += w0 * b2f(u0.y); a2 += w0 * b2f(u0.z); a3 += w0 * b2f(u0.w);
    w0 = w1; u0 = u1;
  }
  const float4 bb = *(const float4*)(bias + c);
  float v0 = a0 * inv + bb.x, v1 = a1 * inv + bb.y, v2 = a2 * inv + bb.z, v3 = a3 * inv + bb.w;
  if (LAYER == 2) {
    ushort4 r = *(const ushort4*)(resid + (size_t)n * DIM2 + c);
    v0 += b2f(r.x); v1 += b2f(r.y); v2 += b2f(r.z); v3 += b2f(r.w);
  }
  v0 = v0 > 0.f ? v0 : __expf(v0) - 1.f;
  v1 = v1 > 0.f ? v1 : __expf(v1) - 1.f;
  v2 = v2 > 0.f ? v2 : __expf(v2) - 1.f;
  v3 = v3 > 0.f ? v3 : __expf(v3) - 1.f;
  ushort4 o;
  o.x = f2b(v0); o.y = f2b(v1); o.z = f2b(v2); o.w = f2b(v3);
  *(ushort4*)(out + (size_t)n * old + c) = o;
}

// ---------------- layer 3: skinny projections, one wave per node ----------------
__global__ __launch_bounds__(256) void k_l3(const u16* __restrict__ h2, const float* __restrict__ x,
    const float* __restrict__ W3, const float* __restrict__ Wres2, const float* __restrict__ Wskip,
    const float* __restrict__ a3s, const float* __restrict__ a3d, const float* __restrict__ b3,
    float* __restrict__ H3p, float* __restrict__ base, float* __restrict__ es3, float* __restrict__ ed3) {
  int wv = threadIdx.x >> 6, lane = threadIdx.x & 63;
  int n = blockIdx.x * 4 + wv;
  if (n >= NN) return;
  float p0 = 0.f, p1 = 0.f, r0 = 0.f, r1 = 0.f;
  const u16* hr = h2 + (size_t)n * DIM;
  for (int c = lane; c < DIM; c += 64) {
    float v = b2f(hr[c]);
    p0 += v * W3[2 * c];    p1 += v * W3[2 * c + 1];
    r0 += v * Wres2[2 * c]; r1 += v * Wres2[2 * c + 1];
  }
  float s0 = 0.f, s1 = 0.f;
  const float* xr = x + (size_t)n * FIN;
  for (int c = lane; c < FIN; c += 64) {
    float v = xr[c];
    s0 += v * Wskip[2 * c]; s1 += v * Wskip[2 * c + 1];
  }
#pragma unroll
  for (int off = 32; off; off >>= 1) {
    p0 += __shfl_down(p0, off); p1 += __shfl_down(p1, off);
    r0 += __shfl_down(r0, off); r1 += __shfl_down(r1, off);
    s0 += __shfl_down(s0, off); s1 += __shfl_down(s1, off);
  }
  if (!lane) {
    H3p[2 * n] = p0; H3p[2 * n + 1] = p1;
    es3[n] = p0 * a3s[0] + p1 * a3s[1];
    ed3[n] = p0 * a3d[0] + p1 * a3d[1];
    base[2 * n]     = r0 + s0 + b3[0];
    base[2 * n + 1] = r1 + s1 + b3[1];
  }
}

// ---------------- layer 3 softmax+aggregate (1 head, 2 ch) -> final logits ----------------
__global__ void k_l3agg(const int* __restrict__ rs, const int* __restrict__ esrc,
                        const float* __restrict__ H3p, const float* __restrict__ base,
                        const float* __restrict__ es3, const float* __restrict__ ed3,
                        float* __restrict__ out) {
  int n = blockIdx.x * 256 + threadIdx.x;
  if (n >= NN) return;
  int beg = rs[n], end = rs[n + 1];
  float edv = ed3[n];
  float den = 0.f, a0 = 0.f, a1 = 0.f;
  for (int j = beg; j < end; ++j) {
    int s = esrc[j];
    float e = es3[s] + edv;
    e = e > 0.f ? e : NEG * e;
    float exv = __expf(e);
    den += exv;
    a0 += exv * H3p[2 * s];
    a1 += exv * H3p[2 * s + 1];
  }
  float inv = 1.f / (den + 1e-16f);
  out[2 * n]     = base[2 * n]     + a0 * inv;
  out[2 * n + 1] = base[2 * n + 1] + a1 * inv;
}

extern "C" void kernel_launch(void* const* d_in, const int* in_sizes, int n_in,
                              void* d_out, int out_size, void* d_ws, size_t ws_size,
                              hipStream_t stream) {
  (void)in_sizes; (void)n_in; (void)out_size; (void)ws_size;
  const float* x    = (const float*)d_in[0];
  const int*   ei   = (const int*)d_in[1];
  const float* W1   = (const float*)d_in[2];
  const float* a1s  = (const float*)d_in[3];
  const float* a1d  = (const float*)d_in[4];
  const float* b1   = (const float*)d_in[5];
  const float* W2   = (const float*)d_in[6];
  const float* a2s  = (const float*)d_in[7];
  const float* a2d  = (const float*)d_in[8];
  const float* b2   = (const float*)d_in[9];
  const float* W3   = (const float*)d_in[10];
  const float* a3s  = (const float*)d_in[11];
  const float* a3d  = (const float*)d_in[12];
  const float* b3   = (const float*)d_in[13];
  const float* Wr1  = (const float*)d_in[14];
  const float* Wr2  = (const float*)d_in[15];
  const float* Wsk  = (const float*)d_in[16];
  float* out = (float*)d_out;

  // ---- workspace layout (~260.9 MB) ----
  char* w = (char*)d_ws;
  size_t off = 0;
  auto alloc = [&](size_t bytes) { void* p = w + off; off += (bytes + 255) & ~(size_t)255; return p; };
  int* cnt   = (int*)alloc((size_t)NN * 4);
  int* cur   = (int*)alloc((size_t)NN * 4);
  int* rs    = (int*)alloc((size_t)(NN + 1) * 4);
  int* bs    = (int*)alloc(256 * 4);
  int* esrc  = (int*)alloc((size_t)ETOT * 4);
  float* es  = (float*)alloc((size_t)NN * HEADS * 4);
  float* ed  = (float*)alloc((size_t)NN * HEADS * 4);
  float* exb = (float*)alloc((size_t)ETOT * HEADS * 4);
  float* dvf = (float*)alloc((size_t)NN * HEADS * 4);
  u16* W2t   = (u16*)alloc((size_t)NP2 * KP2 * 2);
  u16* bufB  = (u16*)alloc((size_t)MPAD * KP2 * 2);    // GEMM2 A (stride KP2), later h2bf (stride DIM)
  u16* bufA  = (u16*)alloc((size_t)NN * DIM2 * 2);     // H1p | A1 | W1t zones, later G2
  u16* H1p   = bufA;                                    // [0, NN*800)
  u16* A1    = bufA + (size_t)NN * DIM;                 // [NN*800, +MPAD*192)
  u16* W1t   = A1 + (size_t)MPAD * KP1;                 // dead before G2
  u16* G2    = bufA;                                    // GEMM2 C, stride 1600, rows < NN
  float* H3p  = exb;
  float* base = exb + 2 * NN;
  float* es3  = exb + 4 * NN;
  float* ed3  = exb + 5 * NN;

  const int nb = (NN + 255) / 256;        // 196
  const int ge = (ETOT + 255) / 256;      // 977
  const int gh = (NN * HEADS + 255) / 256;// 1563

  // CSR build
  hipMemsetAsync(cnt, 0, (size_t)NN * 4, stream);
  hipMemsetAsync(cur, 0, (size_t)NN * 4, stream);
  k_count<<<ge, 256, 0, stream>>>(ei, cnt);
  k_bsum <<<nb, 256, 0, stream>>>(cnt, bs);
  k_top  <<<1, 256, 0, stream>>>(bs, rs, nb);
  k_scan <<<nb, 256, 0, stream>>>(cnt, bs, rs);
  k_fill <<<ge, 256, 0, stream>>>(ei, rs, cur, esrc);

  // converts (+ fused es/ed weight columns)
  k_cvt_x <<<(MPAD * KP1) / 256, 256, 0, stream>>>(x, A1);
  k_cvt_w1<<<(DIM * KP1) / 256, 256, 0, stream>>>(W1, W1t);
  k_wa    <<<(16 * KP1) / 256, 256, 0, stream>>>(W1, a1s, a1d, W1t, FIN, KP1, DIM);
  k_cvt_w2<<<(DIM2 * KP2) / 256, 256, 0, stream>>>(W2, Wr1, W2t);
  k_wa    <<<(16 * KP2) / 256, 256, 0, stream>>>(W2, a2s, a2d, W2t, DIM, KP2, DIM2);

  // layer 1 (GEMM also emits es/ed via fused columns 800-815)
  k_gemm256<<<dim3(NP1 / 256, MPAD / 256), 512, 0, stream>>>(
      A1, W1t, H1p, es, ed, KP1, KP1 / 64, DIM, DIM + 16, DIM, NN);
  k_stats<<<gh, 256, 0, stream>>>(rs, esrc, es, ed, exb, dvf);
  k_agg<1><<<NN, 256, 0, stream>>>(rs, esrc, H1p, exb, dvf, b1, (const u16*)nullptr, bufB);

  // layer 2 (W2|Wres1 fused GEMM; es/ed via fused columns 1600-1615)
  k_gemm256<<<dim3(NP2 / 256, MPAD / 256), 512, 0, stream>>>(
      bufB, W2t, G2, es, ed, KP2, KP2 / 64, DIM2, DIM2 + 16, DIM2, NN);
  k_stats<<<gh, 256, 0, stream>>>(rs, esrc, es, ed, exb, dvf);
  k_agg<2><<<NN, 256, 0, stream>>>(rs, esrc, G2, exb, dvf, b2, G2 + DIM, bufB);

  // layer 3
  k_l3   <<<(NN + 3) / 4, 256, 0, stream>>>(bufB, x, W3, Wr2, Wsk, a3s, a3d, b3, H3p, base, es3, ed3);
  k_l3agg<<<nb, 256, 0, stream>>>(rs, esrc, H3p, base, es3, ed3, out);
}

// Round 10
// 525.391 us; speedup vs baseline: 1.1373x; 1.1373x over previous
//
#include <hip/hip_runtime.h>

#define NN     50000
#define NE     200000
#define ETOT   250000   // NE + NN self-loops
#define FIN    165
#define KP1    192      // FIN padded to mult of 32
#define HEADS  8
#define CH     100
#define DIM    800      // 8*100
#define MPAD   50048    // 391*128
#define NP1    896      // 7*128  (pad of 816: 800 data + 16 es/ed)
#define DIM2   1600     // W2|Wres1 fused output
#define NP2    1664     // 13*128 (pad of 1616: 1600 data + 16 es/ed)
#define NEG    0.2f

typedef unsigned short u16;
typedef unsigned int   u32;
typedef __bf16 bf16x8 __attribute__((ext_vector_type(8)));
typedef float  f32x4  __attribute__((ext_vector_type(4)));

__device__ __forceinline__ u16 f2b(float f) {
  u32 u = __float_as_uint(f);
  u = (u + 0x7FFFu + ((u >> 16) & 1u)) >> 16;   // RNE
  return (u16)u;
}
__device__ __forceinline__ float b2f(u16 u) { return __uint_as_float(((u32)u) << 16); }

// ---------------- CSR build (dst -> list of src), reused by all 3 layers ----------------
__global__ void k_count(const int* __restrict__ ei, int* __restrict__ cnt) {
  int e = blockIdx.x * 256 + threadIdx.x;
  if (e >= ETOT) return;
  int d = (e < NE) ? ei[NE + e] : (e - NE);
  atomicAdd(&cnt[d], 1);
}
__global__ void k_bsum(const int* __restrict__ cnt, int* __restrict__ bs) {
  __shared__ int sm[256];
  int i = blockIdx.x * 256 + threadIdx.x;
  sm[threadIdx.x] = (i < NN) ? cnt[i] : 0;
  __syncthreads();
  for (int off = 128; off; off >>= 1) {
    if (threadIdx.x < off) sm[threadIdx.x] += sm[threadIdx.x + off];
    __syncthreads();
  }
  if (!threadIdx.x) bs[blockIdx.x] = sm[0];
}
__global__ void k_top(int* __restrict__ bs, int* __restrict__ rs, int nb) {
  __shared__ int sm[256];
  int t = threadIdx.x;
  int v = (t < nb) ? bs[t] : 0;
  sm[t] = v; __syncthreads();
  for (int off = 1; off < 256; off <<= 1) {
    int add = (t >= off) ? sm[t - off] : 0;
    __syncthreads();
    sm[t] += add;
    __syncthreads();
  }
  if (t < nb) bs[t] = sm[t] - v;   // exclusive block offsets
  if (!t) rs[NN] = ETOT;
}
__global__ void k_scan(const int* __restrict__ cnt, const int* __restrict__ bs, int* __restrict__ rs) {
  __shared__ int sm[256];
  int t = threadIdx.x, i = blockIdx.x * 256 + t;
  int v = (i < NN) ? cnt[i] : 0;
  sm[t] = v; __syncthreads();
  for (int off = 1; off < 256; off <<= 1) {
    int add = (t >= off) ? sm[t - off] : 0;
    __syncthreads();
    sm[t] += add;
    __syncthreads();
  }
  if (i < NN) rs[i] = bs[blockIdx.x] + sm[t] - v;
}
__global__ void k_fill(const int* __restrict__ ei, const int* __restrict__ rs,
                       int* __restrict__ cur, int* __restrict__ esrc) {
  int e = blockIdx.x * 256 + threadIdx.x;
  if (e >= ETOT) return;
  int s, d;
  if (e < NE) { s = ei[e]; d = ei[NE + e]; } else { s = d = e - NE; }
  int pos = atomicAdd(&cur[d], 1);
  esrc[rs[d] + pos] = s;
}

// ---------------- converts (fp32 -> bf16, pad, transpose weights) ----------------
__global__ void k_cvt_x(const float* __restrict__ x, u16* __restrict__ A) {
  int idx = blockIdx.x * 256 + threadIdx.x;   // MPAD*KP1 exact
  int r = idx / KP1, k = idx - r * KP1;
  float v = (r < NN && k < FIN) ? x[r * FIN + k] : 0.f;
  A[idx] = f2b(v);
}
__global__ void k_cvt_w1(const float* __restrict__ W1, u16* __restrict__ Bt) {
  int idx = blockIdx.x * 256 + threadIdx.x;   // NP1*KP1 exact
  int j = idx / KP1, k = idx - j * KP1;
  float v = (j < DIM && k < FIN) ? W1[k * DIM + j] : 0.f;
  Bt[idx] = f2b(v);
}
__global__ void k_cvt_w2(const float* __restrict__ W2, const float* __restrict__ Wr1,
                         u16* __restrict__ Bt) {
  int idx = blockIdx.x * 256 + threadIdx.x;   // NP2*DIM exact
  int j = idx / DIM, k = idx - j * DIM;
  float v = 0.f;
  if (j < DIM) v = W2[k * DIM + j];
  else if (j < 2 * DIM) v = Wr1[k * DIM + (j - DIM)];
  Bt[idx] = f2b(v);
}
// fused attention columns: Wt row (Dsp+j), j=h -> (W @ a_src blockdiag), j=8+h -> a_dst.
__global__ void k_wa(const float* __restrict__ W, const float* __restrict__ as,
                     const float* __restrict__ ad, u16* __restrict__ Wt,
                     int Kin, int Kpad, int Dsp) {
  int idx = blockIdx.x * 256 + threadIdx.x;
  if (idx >= 16 * Kpad) return;
  int j = idx / Kpad, k = idx - j * Kpad;
  int h = j & 7;
  const float* a = ((j < 8) ? as : ad) + h * CH;
  float s = 0.f;
  if (k < Kin) {
    const float* wr = W + (size_t)k * DIM + h * CH;
    for (int c = 0; c < CH; ++c) s += wr[c] * a[c];
  }
  Wt[(size_t)(Dsp + j) * Kpad + k] = f2b(s);
}

// ---------------- bf16 MFMA GEMM (R4-proven): 128^2 tile, BK=32, 2-phase dbuf ----------------
// T1 XCD swizzle; stage(next) issued before ds_read+MFMA of current; ONE
// __syncthreads per K-step (vmcnt(0)-drain at barrier provides the wait).
// 32KB LDS -> ~5 blocks/CU: implicit wave-level overlap (m114) does the pipelining.
__device__ __forceinline__ void gl_lds16(const u16* g, u16* l) {
  __builtin_amdgcn_global_load_lds((const __attribute__((address_space(1))) void*)g,
                                   (__attribute__((address_space(3))) void*)l, 16, 0, 0);
}

__global__ __launch_bounds__(256) void k_gemm(const u16* __restrict__ A, const u16* __restrict__ Bt,
                                              u16* __restrict__ C, float* __restrict__ es,
                                              float* __restrict__ ed, int ksteps, int K,
                                              int Dsplit, int Nreal, int ldC) {
  __shared__ __align__(16) u16 lA[2][128 * 32];
  __shared__ __align__(16) u16 lB[2][128 * 32];
  int t = threadIdx.x;
  int lane = t & 63, wv = t >> 6;

  // T1 XCD swizzle (bijective chunked, m204)
  int nwg = gridDim.x * gridDim.y;
  int h = blockIdx.y * gridDim.x + blockIdx.x;
  int q = nwg >> 3, r8 = nwg & 7;
  int xcd = h & 7, i8 = h >> 3;
  int ln = (xcd < r8 ? xcd * (q + 1) : r8 * (q + 1) + (xcd - r8) * q) + i8;
  int tn = (ln % gridDim.x) * 128, tm = (ln / gridDim.x) * 128;

  int wr = (wv >> 1) * 64, wc = (wv & 1) * 64;
  int rl = lane & 15, kl = (lane >> 4) * 8;
  int srow = t >> 2, scb = (t & 3) * 8;      // staging: thread -> (row, col-block)

  f32x4 acc[4][4];
#pragma unroll
  for (int i = 0; i < 4; ++i)
#pragma unroll
    for (int j = 0; j < 4; ++j) acc[i][j] = (f32x4){0.f, 0.f, 0.f, 0.f};

  auto stage = [&](int buf, int ks) {
    int k0 = ks * 32;
#pragma unroll
    for (int r = 0; r < 2; ++r) {
      int row = srow + r * 64;
      int chunk = (r * 256 + t) * 8;
      gl_lds16(A + (size_t)(tm + row) * K + k0 + scb, &lA[buf][chunk]);
      gl_lds16(Bt + (size_t)(tn + row) * K + k0 + scb, &lB[buf][chunk]);
    }
  };

  stage(0, 0);
  int cur = 0;
  for (int ks = 0; ks < ksteps; ++ks) {
    __syncthreads();                       // drains vmcnt(0): buf[cur] fully written
    if (ks + 1 < ksteps) stage(cur ^ 1, ks + 1);   // loads fly under the MFMAs below
    bf16x8 af[4], bfr[4];
#pragma unroll
    for (int i = 0; i < 4; ++i) {
      af[i]  = *(const bf16x8*)&lA[cur][(wr + i * 16 + rl) * 32 + kl];
      bfr[i] = *(const bf16x8*)&lB[cur][(wc + i * 16 + rl) * 32 + kl];
    }
#pragma unroll
    for (int i = 0; i < 4; ++i)
#pragma unroll
      for (int j = 0; j < 4; ++j)
        acc[i][j] = __builtin_amdgcn_mfma_f32_16x16x32_bf16(af[i], bfr[j], acc[i][j], 0, 0, 0);
    cur ^= 1;
  }
  int rq = (lane >> 4) * 4;
#pragma unroll
  for (int i = 0; i < 4; ++i) {
#pragma unroll
    for (int j = 0; j < 4; ++j) {
      int col = tn + wc + j * 16 + rl;
      if (col < Dsplit) {
#pragma unroll
        for (int q2 = 0; q2 < 4; ++q2) {
          int row = tm + wr + i * 16 + rq + q2;
          C[(size_t)row * ldC + col] = f2b(acc[i][j][q2]);
        }
      } else if (col < Nreal) {
        int cj = col - Dsplit;
        float* dst = (cj < 8) ? es : ed;
        int hh = cj & 7;
#pragma unroll
        for (int q2 = 0; q2 < 4; ++q2) {
          int row = tm + wr + i * 16 + rq + q2;
          dst[(size_t)row * 8 + hh] = acc[i][j][q2];
        }
      }
    }
  }
}

// ---- per-(node,head) softmax stats; single pass (shift-invariant, m=0), stores exp ----
__global__ void k_stats(const int* __restrict__ rs, const int* __restrict__ esrc,
                        const float* __restrict__ es, const float* __restrict__ ed,
                        float* __restrict__ ex, float* __restrict__ dv) {
  int idx = blockIdx.x * 256 + threadIdx.x;
  if (idx >= NN * HEADS) return;
  int n = idx >> 3, h = idx & 7;
  int beg = rs[n], end = rs[n + 1];
  float edv = ed[idx];
  float den = 0.f;
  for (int j = beg; j < end; ++j) {
    float x = es[esrc[j] * 8 + h] + edv;
    x = x > 0.f ? x : NEG * x;
    float e = __expf(x);
    ex[j * 8 + h] = e;
    den += e;
  }
  dv[idx] = 1.f / (den + 1e-16f);
}

// ---- layer-1 aggregation (R4-proven): ex-broadcast + ushort4 gather + FMA; writes h1 ----
__global__ __launch_bounds__(256) void k_agg1(const int* __restrict__ rs, const int* __restrict__ esrc,
    const u16* __restrict__ Hp, const float* __restrict__ ex, const float* __restrict__ dv,
    const float* __restrict__ bias, u16* __restrict__ out) {
  int n = blockIdx.x, t = threadIdx.x;
  if (t >= 200) return;
  int beg = rs[n], end = rs[n + 1];
  int c = t * 4;
  int h = t / 25;
  float inv = dv[n * 8 + h];
  float a0 = 0.f, a1 = 0.f, a2 = 0.f, a3 = 0.f;
  for (int j = beg; j < end; ++j) {
    int s = esrc[j];
    float w = ex[j * 8 + h];
    ushort4 u = *(const ushort4*)(Hp + (size_t)s * DIM + c);
    a0 += w * b2f(u.x); a1 += w * b2f(u.y); a2 += w * b2f(u.z); a3 += w * b2f(u.w);
  }
  const float4 bb = *(const float4*)(bias + c);
  float v0 = a0 * inv + bb.x, v1 = a1 * inv + bb.y, v2 = a2 * inv + bb.z, v3 = a3 * inv + bb.w;
  v0 = v0 > 0.f ? v0 : __expf(v0) - 1.f;
  v1 = v1 > 0.f ? v1 : __expf(v1) - 1.f;
  v2 = v2 > 0.f ? v2 : __expf(v2) - 1.f;
  v3 = v3 > 0.f ? v3 : __expf(v3) - 1.f;
  ushort4 o;
  o.x = f2b(v0); o.y = f2b(v1); o.z = f2b(v2); o.w = f2b(v3);
  *(ushort4*)(out + (size_t)n * DIM + c) = o;
}

// ---- layer-2 aggregation FUSED with layer-3 projections: h2 never materialized ----
// Computes h2 row in registers (agg + bias + resid + ELU, fp32), then directly the
// three skinny dots (h2@W3 -> H3p/es3/ed3, h2@Wres2 -> base with x@Wskip from skp).
// No early return before barriers: work guarded by t<200.
__global__ __launch_bounds__(256) void k_agg2f(const int* __restrict__ rs, const int* __restrict__ esrc,
    const u16* __restrict__ Hp, const float* __restrict__ ex, const float* __restrict__ dv,
    const float* __restrict__ bias, const u16* __restrict__ resid,
    const float* __restrict__ W3, const float* __restrict__ Wres2,
    const float* __restrict__ a3s, const float* __restrict__ a3d, const float* __restrict__ b3,
    const float* __restrict__ skp,
    float* __restrict__ H3p, float* __restrict__ base,
    float* __restrict__ es3, float* __restrict__ ed3) {
  int n = blockIdx.x, t = threadIdx.x;
  int lane = t & 63, wv = t >> 6;
  float p0 = 0.f, p1 = 0.f, r0 = 0.f, r1 = 0.f;
  if (t < 200) {
    int beg = rs[n], end = rs[n + 1];
    int c = t * 4;
    int h = t / 25;
    float inv = dv[n * 8 + h];
    float a0 = 0.f, a1 = 0.f, a2 = 0.f, a3 = 0.f;
    for (int j = beg; j < end; ++j) {
      int s = esrc[j];
      float w = ex[j * 8 + h];
      ushort4 u = *(const ushort4*)(Hp + (size_t)s * DIM2 + c);
      a0 += w * b2f(u.x); a1 += w * b2f(u.y); a2 += w * b2f(u.z); a3 += w * b2f(u.w);
    }
    const float4 bb = *(const float4*)(bias + c);
    ushort4 rr = *(const ushort4*)(resid + (size_t)n * DIM2 + c);
    float v0 = a0 * inv + bb.x + b2f(rr.x);
    float v1 = a1 * inv + bb.y + b2f(rr.y);
    float v2 = a2 * inv + bb.z + b2f(rr.z);
    float v3 = a3 * inv + bb.w + b2f(rr.w);
    v0 = v0 > 0.f ? v0 : __expf(v0) - 1.f;
    v1 = v1 > 0.f ? v1 : __expf(v1) - 1.f;
    v2 = v2 > 0.f ? v2 : __expf(v2) - 1.f;
    v3 = v3 > 0.f ? v3 : __expf(v3) - 1.f;
    // skinny dots: W3/Wres2 are [800][2] row-major; rows c..c+3 = 8 consecutive floats
    const float4 w3a = *(const float4*)(W3 + 2 * c);
    const float4 w3b = *(const float4*)(W3 + 2 * c + 4);
    const float4 wra = *(const float4*)(Wres2 + 2 * c);
    const float4 wrb = *(const float4*)(Wres2 + 2 * c + 4);
    p0 = v0 * w3a.x + v1 * w3a.z + v2 * w3b.x + v3 * w3b.z;
    p1 = v0 * w3a.y + v1 * w3a.w + v2 * w3b.y + v3 * w3b.w;
    r0 = v0 * wra.x + v1 * wra.z + v2 * wrb.x + v3 * wrb.z;
    r1 = v0 * wra.y + v1 * wra.w + v2 * wrb.y + v3 * wrb.w;
  }
#pragma unroll
  for (int off = 32; off; off >>= 1) {
    p0 += __shfl_down(p0, off); p1 += __shfl_down(p1, off);
    r0 += __shfl_down(r0, off); r1 += __shfl_down(r1, off);
  }
  __shared__ float red[4][4];
  if (!lane) { red[wv][0] = p0; red[wv][1] = p1; red[wv][2] = r0; red[wv][3] = r1; }
  __syncthreads();
  if (!t) {
    float P0 = red[0][0] + red[1][0] + red[2][0] + red[3][0];
    float P1 = red[0][1] + red[1][1] + red[2][1] + red[3][1];
    float R0 = red[0][2] + red[1][2] + red[2][2] + red[3][2];
    float R1 = red[0][3] + red[1][3] + red[2][3] + red[3][3];
    H3p[2 * n] = P0; H3p[2 * n + 1] = P1;
    es3[n] = P0 * a3s[0] + P1 * a3s[1];
    ed3[n] = P0 * a3d[0] + P1 * a3d[1];
    base[2 * n]     = R0 + skp[2 * n]     + b3[0];
    base[2 * n + 1] = R1 + skp[2 * n + 1] + b3[1];
  }
}

// ---------------- x @ Wskip (independent of GAT layers; runs early) ----------------
__global__ __launch_bounds__(256) void k_l3x(const float* __restrict__ x,
    const float* __restrict__ Wskip, float* __restrict__ skp) {
  int wv = threadIdx.x >> 6, lane = threadIdx.x & 63;
  int n = blockIdx.x * 4 + wv;
  if (n >= NN) return;
  float s0 = 0.f, s1 = 0.f;
  const float* xr = x + (size_t)n * FIN;
  for (int c = lane; c < FIN; c += 64) {
    float v = xr[c];
    s0 += v * Wskip[2 * c]; s1 += v * Wskip[2 * c + 1];
  }
#pragma unroll
  for (int off = 32; off; off >>= 1) {
    s0 += __shfl_down(s0, off); s1 += __shfl_down(s1, off);
  }
  if (!lane) { skp[2 * n] = s0; skp[2 * n + 1] = s1; }
}

// ---------------- layer 3 softmax+aggregate (1 head, 2 ch) -> final logits ----------------
__global__ void k_l3agg(const int* __restrict__ rs, const int* __restrict__ esrc,
                        const float* __restrict__ H3p, const float* __restrict__ base,
                        const float* __restrict__ es3, const float* __restrict__ ed3,
                        float* __restrict__ out) {
  int n = blockIdx.x * 256 + threadIdx.x;
  if (n >= NN) return;
  int beg = rs[n], end = rs[n + 1];
  float edv = ed3[n];
  float den = 0.f, a0 = 0.f, a1 = 0.f;
  for (int j = beg; j < end; ++j) {
    int s = esrc[j];
    float e = es3[s] + edv;
    e = e > 0.f ? e : NEG * e;
    float exv = __expf(e);
    den += exv;
    a0 += exv * H3p[2 * s];
    a1 += exv * H3p[2 * s + 1];
  }
  float inv = 1.f / (den + 1e-16f);
  out[2 * n]     = base[2 * n]     + a0 * inv;
  out[2 * n + 1] = base[2 * n + 1] + a1 * inv;
}

extern "C" void kernel_launch(void* const* d_in, const int* in_sizes, int n_in,
                              void* d_out, int out_size, void* d_ws, size_t ws_size,
                              hipStream_t stream) {
  (void)in_sizes; (void)n_in; (void)out_size; (void)ws_size;
  const float* x    = (const float*)d_in[0];
  const int*   ei   = (const int*)d_in[1];
  const float* W1   = (const float*)d_in[2];
  const float* a1s  = (const float*)d_in[3];
  const float* a1d  = (const float*)d_in[4];
  const float* b1   = (const float*)d_in[5];
  const float* W2   = (const float*)d_in[6];
  const float* a2s  = (const float*)d_in[7];
  const float* a2d  = (const float*)d_in[8];
  const float* b2   = (const float*)d_in[9];
  const float* W3   = (const float*)d_in[10];
  const float* a3s  = (const float*)d_in[11];
  const float* a3d  = (const float*)d_in[12];
  const float* b3   = (const float*)d_in[13];
  const float* Wr1  = (const float*)d_in[14];
  const float* Wr2  = (const float*)d_in[15];
  const float* Wsk  = (const float*)d_in[16];
  float* out = (float*)d_out;

  // ---- workspace (~259.3 MB, R4 layout + skp) ----
  char* w = (char*)d_ws;
  size_t off = 0;
  auto alloc = [&](size_t bytes) { void* p = w + off; off += (bytes + 255) & ~(size_t)255; return p; };
  int* cnt   = (int*)alloc((size_t)NN * 4);
  int* cur   = (int*)alloc((size_t)NN * 4);
  int* rs    = (int*)alloc((size_t)(NN + 1) * 4);
  int* bs    = (int*)alloc(256 * 4);
  int* esrc  = (int*)alloc((size_t)ETOT * 4);
  float* es  = (float*)alloc((size_t)MPAD * HEADS * 4);
  float* ed  = (float*)alloc((size_t)MPAD * HEADS * 4);
  float* exb = (float*)alloc((size_t)ETOT * HEADS * 4);
  float* dvf = (float*)alloc((size_t)NN * HEADS * 4);
  u16* W1t   = (u16*)alloc((size_t)NP1 * KP1 * 2);
  u16* W2t   = (u16*)alloc((size_t)NP2 * DIM * 2);
  float* H3p = (float*)alloc((size_t)NN * 2 * 4);
  float* base= (float*)alloc((size_t)NN * 2 * 4);
  float* es3 = (float*)alloc((size_t)NN * 4);
  float* ed3 = (float*)alloc((size_t)NN * 4);
  float* skp = (float*)alloc((size_t)NN * 2 * 4);
  u16* bufB  = (u16*)alloc((size_t)MPAD * DIM * 2);    // h1bf (GEMM2 A)
  u16* bufA  = (u16*)alloc((size_t)MPAD * DIM2 * 2);   // H1p, later G2 (fused proj|resid)
  u16* H1p   = bufA;
  u16* G2    = bufA;
  u16* A1    = bufA + (size_t)MPAD * DIM;              // alias upper half of bufA (dead before G2)

  const int nb = (NN + 255) / 256;        // 196
  const int ge = (ETOT + 255) / 256;      // 977
  const int gh = (NN * HEADS + 255) / 256;// 1563

  // CSR build
  hipMemsetAsync(cnt, 0, (size_t)NN * 4, stream);
  hipMemsetAsync(cur, 0, (size_t)NN * 4, stream);
  k_count<<<ge, 256, 0, stream>>>(ei, cnt);
  k_bsum <<<nb, 256, 0, stream>>>(cnt, bs);
  k_top  <<<1, 256, 0, stream>>>(bs, rs, nb);
  k_scan <<<nb, 256, 0, stream>>>(cnt, bs, rs);
  k_fill <<<ge, 256, 0, stream>>>(ei, rs, cur, esrc);

  // converts (+ fused es/ed weight columns) + x@Wskip
  k_cvt_x <<<(MPAD * KP1) / 256, 256, 0, stream>>>(x, A1);
  k_cvt_w1<<<(NP1 * KP1) / 256, 256, 0, stream>>>(W1, W1t);
  k_wa    <<<(16 * KP1 + 255) / 256, 256, 0, stream>>>(W1, a1s, a1d, W1t, FIN, KP1, DIM);
  k_cvt_w2<<<(NP2 * DIM) / 256, 256, 0, stream>>>(W2, Wr1, W2t);
  k_wa    <<<(16 * DIM + 255) / 256, 256, 0, stream>>>(W2, a2s, a2d, W2t, DIM, DIM, DIM2);
  k_l3x   <<<(NN + 3) / 4, 256, 0, stream>>>(x, Wsk, skp);

  // layer 1 (GEMM also emits es/ed via fused columns 800-815)
  k_gemm<<<dim3(NP1 / 128, MPAD / 128), 256, 0, stream>>>(A1, W1t, H1p, es, ed,
                                                          KP1 / 32, KP1, DIM, DIM + 16, DIM);
  k_stats<<<gh, 256, 0, stream>>>(rs, esrc, es, ed, exb, dvf);
  k_agg1<<<NN, 256, 0, stream>>>(rs, esrc, H1p, exb, dvf, b1, bufB);

  // layer 2 (W2|Wres1 fused GEMM; es/ed via fused columns 1600-1615)
  k_gemm<<<dim3(NP2 / 128, MPAD / 128), 256, 0, stream>>>(bufB, W2t, G2, es, ed,
                                                          DIM / 32, DIM, DIM2, DIM2 + 16, DIM2);
  k_stats<<<gh, 256, 0, stream>>>(rs, esrc, es, ed, exb, dvf);
  k_agg2f<<<NN, 256, 0, stream>>>(rs, esrc, G2, exb, dvf, b2, G2 + DIM,
                                  W3, Wr2, a3s, a3d, b3, skp, H3p, base, es3, ed3);

  // layer 3 softmax-aggregate
  k_l3agg<<<nb, 256, 0, stream>>>(rs, esrc, H3p, base, es3, ed3, out);
}

// Round 11
// 508.214 us; speedup vs baseline: 1.1757x; 1.0338x over previous
//
#include <hip/hip_runtime.h>

#define NN     50000
#define NE     200000
#define ETOT   250000   // NE + NN self-loops
#define FIN    165
#define KP1    192      // FIN padded to mult of 32
#define HEADS  8
#define CH     100
#define DIM    800      // 8*100
#define MPAD   50048    // 391*128
#define NP1    896      // 7*128  (pad of 816: 800 data + 16 es/ed)
#define DIM2   1600     // W2|Wres1 fused output
#define NP2    1664     // 13*128 (pad of 1616: 1600 data + 16 es/ed)
#define NEG    0.2f
#define CHK    64       // agg softmax chunk (LDS ex buffer = CHK*8 floats)

typedef unsigned short u16;
typedef unsigned int   u32;
typedef __bf16 bf16x8 __attribute__((ext_vector_type(8)));
typedef float  f32x4  __attribute__((ext_vector_type(4)));

__device__ __forceinline__ u16 f2b(float f) {
  u32 u = __float_as_uint(f);
  u = (u + 0x7FFFu + ((u >> 16) & 1u)) >> 16;   // RNE
  return (u16)u;
}
__device__ __forceinline__ float b2f(u16 u) { return __uint_as_float(((u32)u) << 16); }

// ---------------- CSR build (dst -> list of src), reused by all 3 layers ----------------
__global__ void k_count(const int* __restrict__ ei, int* __restrict__ cnt) {
  int e = blockIdx.x * 256 + threadIdx.x;
  if (e >= ETOT) return;
  int d = (e < NE) ? ei[NE + e] : (e - NE);
  atomicAdd(&cnt[d], 1);
}
__global__ void k_bsum(const int* __restrict__ cnt, int* __restrict__ bs) {
  __shared__ int sm[256];
  int i = blockIdx.x * 256 + threadIdx.x;
  sm[threadIdx.x] = (i < NN) ? cnt[i] : 0;
  __syncthreads();
  for (int off = 128; off; off >>= 1) {
    if (threadIdx.x < off) sm[threadIdx.x] += sm[threadIdx.x + off];
    __syncthreads();
  }
  if (!threadIdx.x) bs[blockIdx.x] = sm[0];
}
__global__ void k_top(int* __restrict__ bs, int* __restrict__ rs, int nb) {
  __shared__ int sm[256];
  int t = threadIdx.x;
  int v = (t < nb) ? bs[t] : 0;
  sm[t] = v; __syncthreads();
  for (int off = 1; off < 256; off <<= 1) {
    int add = (t >= off) ? sm[t - off] : 0;
    __syncthreads();
    sm[t] += add;
    __syncthreads();
  }
  if (t < nb) bs[t] = sm[t] - v;   // exclusive block offsets
  if (!t) rs[NN] = ETOT;
}
__global__ void k_scan(const int* __restrict__ cnt, const int* __restrict__ bs, int* __restrict__ rs) {
  __shared__ int sm[256];
  int t = threadIdx.x, i = blockIdx.x * 256 + t;
  int v = (i < NN) ? cnt[i] : 0;
  sm[t] = v; __syncthreads();
  for (int off = 1; off < 256; off <<= 1) {
    int add = (t >= off) ? sm[t - off] : 0;
    __syncthreads();
    sm[t] += add;
    __syncthreads();
  }
  if (i < NN) rs[i] = bs[blockIdx.x] + sm[t] - v;
}
__global__ void k_fill(const int* __restrict__ ei, const int* __restrict__ rs,
                       int* __restrict__ cur, int* __restrict__ esrc) {
  int e = blockIdx.x * 256 + threadIdx.x;
  if (e >= ETOT) return;
  int s, d;
  if (e < NE) { s = ei[e]; d = ei[NE + e]; } else { s = d = e - NE; }
  int pos = atomicAdd(&cur[d], 1);
  esrc[rs[d] + pos] = s;
}

// ---------------- converts (fp32 -> bf16, pad, transpose weights) ----------------
__global__ void k_cvt_x(const float* __restrict__ x, u16* __restrict__ A) {
  int idx = blockIdx.x * 256 + threadIdx.x;   // MPAD*KP1 exact
  int r = idx / KP1, k = idx - r * KP1;
  float v = (r < NN && k < FIN) ? x[r * FIN + k] : 0.f;
  A[idx] = f2b(v);
}
__global__ void k_cvt_w1(const float* __restrict__ W1, u16* __restrict__ Bt) {
  int idx = blockIdx.x * 256 + threadIdx.x;   // NP1*KP1 exact
  int j = idx / KP1, k = idx - j * KP1;
  float v = (j < DIM && k < FIN) ? W1[k * DIM + j] : 0.f;
  Bt[idx] = f2b(v);
}
__global__ void k_cvt_w2(const float* __restrict__ W2, const float* __restrict__ Wr1,
                         u16* __restrict__ Bt) {
  int idx = blockIdx.x * 256 + threadIdx.x;   // NP2*DIM exact
  int j = idx / DIM, k = idx - j * DIM;
  float v = 0.f;
  if (j < DIM) v = W2[k * DIM + j];
  else if (j < 2 * DIM) v = Wr1[k * DIM + (j - DIM)];
  Bt[idx] = f2b(v);
}
// fused attention columns: Wt row (Dsp+j), j=h -> (W @ a_src blockdiag), j=8+h -> a_dst.
__global__ void k_wa(const float* __restrict__ W, const float* __restrict__ as,
                     const float* __restrict__ ad, u16* __restrict__ Wt,
                     int Kin, int Kpad, int Dsp) {
  int idx = blockIdx.x * 256 + threadIdx.x;
  if (idx >= 16 * Kpad) return;
  int j = idx / Kpad, k = idx - j * Kpad;
  int h = j & 7;
  const float* a = ((j < 8) ? as : ad) + h * CH;
  float s = 0.f;
  if (k < Kin) {
    const float* wr = W + (size_t)k * DIM + h * CH;
    for (int c = 0; c < CH; ++c) s += wr[c] * a[c];
  }
  Wt[(size_t)(Dsp + j) * Kpad + k] = f2b(s);
}

// ---------------- bf16 MFMA GEMM (R4-proven): 128^2 tile, BK=32, 2-phase dbuf ----------------
__device__ __forceinline__ void gl_lds16(const u16* g, u16* l) {
  __builtin_amdgcn_global_load_lds((const __attribute__((address_space(1))) void*)g,
                                   (__attribute__((address_space(3))) void*)l, 16, 0, 0);
}

__global__ __launch_bounds__(256) void k_gemm(const u16* __restrict__ A, const u16* __restrict__ Bt,
                                              u16* __restrict__ C, float* __restrict__ es,
                                              float* __restrict__ ed, int ksteps, int K,
                                              int Dsplit, int Nreal, int ldC) {
  __shared__ __align__(16) u16 lA[2][128 * 32];
  __shared__ __align__(16) u16 lB[2][128 * 32];
  int t = threadIdx.x;
  int lane = t & 63, wv = t >> 6;

  // T1 XCD swizzle (bijective chunked, m204)
  int nwg = gridDim.x * gridDim.y;
  int h = blockIdx.y * gridDim.x + blockIdx.x;
  int q = nwg >> 3, r8 = nwg & 7;
  int xcd = h & 7, i8 = h >> 3;
  int ln = (xcd < r8 ? xcd * (q + 1) : r8 * (q + 1) + (xcd - r8) * q) + i8;
  int tn = (ln % gridDim.x) * 128, tm = (ln / gridDim.x) * 128;

  int wr = (wv >> 1) * 64, wc = (wv & 1) * 64;
  int rl = lane & 15, kl = (lane >> 4) * 8;
  int srow = t >> 2, scb = (t & 3) * 8;      // staging: thread -> (row, col-block)

  f32x4 acc[4][4];
#pragma unroll
  for (int i = 0; i < 4; ++i)
#pragma unroll
    for (int j = 0; j < 4; ++j) acc[i][j] = (f32x4){0.f, 0.f, 0.f, 0.f};

  auto stage = [&](int buf, int ks) {
    int k0 = ks * 32;
#pragma unroll
    for (int r = 0; r < 2; ++r) {
      int row = srow + r * 64;
      int chunk = (r * 256 + t) * 8;
      gl_lds16(A + (size_t)(tm + row) * K + k0 + scb, &lA[buf][chunk]);
      gl_lds16(Bt + (size_t)(tn + row) * K + k0 + scb, &lB[buf][chunk]);
    }
  };

  stage(0, 0);
  int cur = 0;
  for (int ks = 0; ks < ksteps; ++ks) {
    __syncthreads();                       // drains vmcnt(0): buf[cur] fully written
    if (ks + 1 < ksteps) stage(cur ^ 1, ks + 1);   // loads fly under the MFMAs below
    bf16x8 af[4], bfr[4];
#pragma unroll
    for (int i = 0; i < 4; ++i) {
      af[i]  = *(const bf16x8*)&lA[cur][(wr + i * 16 + rl) * 32 + kl];
      bfr[i] = *(const bf16x8*)&lB[cur][(wc + i * 16 + rl) * 32 + kl];
    }
#pragma unroll
    for (int i = 0; i < 4; ++i)
#pragma unroll
      for (int j = 0; j < 4; ++j)
        acc[i][j] = __builtin_amdgcn_mfma_f32_16x16x32_bf16(af[i], bfr[j], acc[i][j], 0, 0, 0);
    cur ^= 1;
  }
  int rq = (lane >> 4) * 4;
#pragma unroll
  for (int i = 0; i < 4; ++i) {
#pragma unroll
    for (int j = 0; j < 4; ++j) {
      int col = tn + wc + j * 16 + rl;
      if (col < Dsplit) {
#pragma unroll
        for (int q2 = 0; q2 < 4; ++q2) {
          int row = tm + wr + i * 16 + rq + q2;
          C[(size_t)row * ldC + col] = f2b(acc[i][j][q2]);
        }
      } else if (col < Nreal) {
        int cj = col - Dsplit;
        float* dst = (cj < 8) ? es : ed;
        int hh = cj & 7;
#pragma unroll
        for (int q2 = 0; q2 < 4; ++q2) {
          int row = tm + wr + i * 16 + rq + q2;
          dst[(size_t)row * 8 + hh] = acc[i][j][q2];
        }
      }
    }
  }
}

// ==== fused softmax-stats + aggregation (chunked in-LDS) ====
// Per 64-edge chunk: all 256 threads compute ex[(edge,head)] -> LDS (+den via LDS
// float atomics), barrier, then 200 agg threads consume ex from LDS. Denominator
// (1/den) applied once at the end (distributive). No exb/dvf global round-trip.

// ---- layer-1: writes h1 (GEMM2 A-matrix) ----
__global__ __launch_bounds__(256) void k_agg1(const int* __restrict__ rs, const int* __restrict__ esrc,
    const u16* __restrict__ Hp, const float* __restrict__ es, const float* __restrict__ ed,
    const float* __restrict__ bias, u16* __restrict__ out) {
  __shared__ float sm_ex[CHK * 8];
  __shared__ float sm_den[8];
  __shared__ int   sm_src[CHK];
  int n = blockIdx.x, t = threadIdx.x;
  if (t < 8) sm_den[t] = 0.f;
  int beg = rs[n], end = rs[n + 1];
  int c = t * 4;
  int h = t / 25;
  float edv = (t < 200) ? 0.f : 0.f;
  // per-head ed broadcast via registers: all ex-threads read ed[n*8+hh] directly (L1-hot)
  float a0 = 0.f, a1 = 0.f, a2 = 0.f, a3 = 0.f;
  __syncthreads();
  for (int ch = beg; ch < end; ch += CHK) {
    int ce = min(end, ch + CHK);
    int m = ce - ch;
    if (t < m) sm_src[t] = esrc[ch + t];
    __syncthreads();
    for (int i = t; i < m * 8; i += 256) {
      int e8 = i >> 3, hh = i & 7;
      float xv = es[sm_src[e8] * 8 + hh] + ed[n * 8 + hh];
      xv = xv > 0.f ? xv : NEG * xv;
      float e = __expf(xv);
      sm_ex[i] = e;
      atomicAdd(&sm_den[hh], e);
    }
    __syncthreads();
    if (t < 200) {
      for (int j = 0; j < m; ++j) {
        float w = sm_ex[j * 8 + h];
        ushort4 u = *(const ushort4*)(Hp + (size_t)sm_src[j] * DIM + c);
        a0 += w * b2f(u.x); a1 += w * b2f(u.y); a2 += w * b2f(u.z); a3 += w * b2f(u.w);
      }
    }
    __syncthreads();
  }
  if (t >= 200) return;
  float inv = 1.f / (sm_den[h] + 1e-16f);
  const float4 bb = *(const float4*)(bias + c);
  float v0 = a0 * inv + bb.x, v1 = a1 * inv + bb.y, v2 = a2 * inv + bb.z, v3 = a3 * inv + bb.w;
  v0 = v0 > 0.f ? v0 : __expf(v0) - 1.f;
  v1 = v1 > 0.f ? v1 : __expf(v1) - 1.f;
  v2 = v2 > 0.f ? v2 : __expf(v2) - 1.f;
  v3 = v3 > 0.f ? v3 : __expf(v3) - 1.f;
  ushort4 o;
  o.x = f2b(v0); o.y = f2b(v1); o.z = f2b(v2); o.w = f2b(v3);
  *(ushort4*)(out + (size_t)n * DIM + c) = o;
  (void)edv;
}

// ---- layer-2: fused stats + agg + resid + ELU + layer-3 skinny projections ----
// h2 never materialized. All barriers reached by all 256 threads (work guarded).
__global__ __launch_bounds__(256) void k_agg2f(const int* __restrict__ rs, const int* __restrict__ esrc,
    const u16* __restrict__ Hp, const float* __restrict__ es, const float* __restrict__ ed,
    const float* __restrict__ bias, const u16* __restrict__ resid,
    const float* __restrict__ W3, const float* __restrict__ Wres2,
    const float* __restrict__ a3s, const float* __restrict__ a3d, const float* __restrict__ b3,
    const float* __restrict__ skp,
    float* __restrict__ H3p, float* __restrict__ base,
    float* __restrict__ es3, float* __restrict__ ed3) {
  __shared__ float sm_ex[CHK * 8];
  __shared__ float sm_den[8];
  __shared__ int   sm_src[CHK];
  __shared__ float red[4][4];
  int n = blockIdx.x, t = threadIdx.x;
  int lane = t & 63, wv = t >> 6;
  if (t < 8) sm_den[t] = 0.f;
  int beg = rs[n], end = rs[n + 1];
  int c = t * 4;
  int h = t / 25;
  float a0 = 0.f, a1 = 0.f, a2 = 0.f, a3 = 0.f;
  __syncthreads();
  for (int ch = beg; ch < end; ch += CHK) {
    int ce = min(end, ch + CHK);
    int m = ce - ch;
    if (t < m) sm_src[t] = esrc[ch + t];
    __syncthreads();
    for (int i = t; i < m * 8; i += 256) {
      int e8 = i >> 3, hh = i & 7;
      float xv = es[sm_src[e8] * 8 + hh] + ed[n * 8 + hh];
      xv = xv > 0.f ? xv : NEG * xv;
      float e = __expf(xv);
      sm_ex[i] = e;
      atomicAdd(&sm_den[hh], e);
    }
    __syncthreads();
    if (t < 200) {
      for (int j = 0; j < m; ++j) {
        float w = sm_ex[j * 8 + h];
        ushort4 u = *(const ushort4*)(Hp + (size_t)sm_src[j] * DIM2 + c);
        a0 += w * b2f(u.x); a1 += w * b2f(u.y); a2 += w * b2f(u.z); a3 += w * b2f(u.w);
      }
    }
    __syncthreads();
  }
  float p0 = 0.f, p1 = 0.f, r0 = 0.f, r1 = 0.f;
  if (t < 200) {
    float inv = 1.f / (sm_den[h] + 1e-16f);
    const float4 bb = *(const float4*)(bias + c);
    ushort4 rr = *(const ushort4*)(resid + (size_t)n * DIM2 + c);
    float v0 = a0 * inv + bb.x + b2f(rr.x);
    float v1 = a1 * inv + bb.y + b2f(rr.y);
    float v2 = a2 * inv + bb.z + b2f(rr.z);
    float v3 = a3 * inv + bb.w + b2f(rr.w);
    v0 = v0 > 0.f ? v0 : __expf(v0) - 1.f;
    v1 = v1 > 0.f ? v1 : __expf(v1) - 1.f;
    v2 = v2 > 0.f ? v2 : __expf(v2) - 1.f;
    v3 = v3 > 0.f ? v3 : __expf(v3) - 1.f;
    // skinny dots: W3/Wres2 are [800][2] row-major; rows c..c+3 = 8 consecutive floats
    const float4 w3a = *(const float4*)(W3 + 2 * c);
    const float4 w3b = *(const float4*)(W3 + 2 * c + 4);
    const float4 wra = *(const float4*)(Wres2 + 2 * c);
    const float4 wrb = *(const float4*)(Wres2 + 2 * c + 4);
    p0 = v0 * w3a.x + v1 * w3a.z + v2 * w3b.x + v3 * w3b.z;
    p1 = v0 * w3a.y + v1 * w3a.w + v2 * w3b.y + v3 * w3b.w;
    r0 = v0 * wra.x + v1 * wra.z + v2 * wrb.x + v3 * wrb.z;
    r1 = v0 * wra.y + v1 * wra.w + v2 * wrb.y + v3 * wrb.w;
  }
#pragma unroll
  for (int off = 32; off; off >>= 1) {
    p0 += __shfl_down(p0, off); p1 += __shfl_down(p1, off);
    r0 += __shfl_down(r0, off); r1 += __shfl_down(r1, off);
  }
  if (!lane) { red[wv][0] = p0; red[wv][1] = p1; red[wv][2] = r0; red[wv][3] = r1; }
  __syncthreads();
  if (!t) {
    float P0 = red[0][0] + red[1][0] + red[2][0] + red[3][0];
    float P1 = red[0][1] + red[1][1] + red[2][1] + red[3][1];
    float R0 = red[0][2] + red[1][2] + red[2][2] + red[3][2];
    float R1 = red[0][3] + red[1][3] + red[2][3] + red[3][3];
    H3p[2 * n] = P0; H3p[2 * n + 1] = P1;
    es3[n] = P0 * a3s[0] + P1 * a3s[1];
    ed3[n] = P0 * a3d[0] + P1 * a3d[1];
    base[2 * n]     = R0 + skp[2 * n]     + b3[0];
    base[2 * n + 1] = R1 + skp[2 * n + 1] + b3[1];
  }
}

// ---------------- x @ Wskip (independent of GAT layers; runs early) ----------------
__global__ __launch_bounds__(256) void k_l3x(const float* __restrict__ x,
    const float* __restrict__ Wskip, float* __restrict__ skp) {
  int wv = threadIdx.x >> 6, lane = threadIdx.x & 63;
  int n = blockIdx.x * 4 + wv;
  if (n >= NN) return;
  float s0 = 0.f, s1 = 0.f;
  const float* xr = x + (size_t)n * FIN;
  for (int c = lane; c < FIN; c += 64) {
    float v = xr[c];
    s0 += v * Wskip[2 * c]; s1 += v * Wskip[2 * c + 1];
  }
#pragma unroll
  for (int off = 32; off; off >>= 1) {
    s0 += __shfl_down(s0, off); s1 += __shfl_down(s1, off);
  }
  if (!lane) { skp[2 * n] = s0; skp[2 * n + 1] = s1; }
}

// ---------------- layer 3 softmax+aggregate (1 head, 2 ch) -> final logits ----------------
__global__ void k_l3agg(const int* __restrict__ rs, const int* __restrict__ esrc,
                        const float* __restrict__ H3p, const float* __restrict__ base,
                        const float* __restrict__ es3, const float* __restrict__ ed3,
                        float* __restrict__ out) {
  int n = blockIdx.x * 256 + threadIdx.x;
  if (n >= NN) return;
  int beg = rs[n], end = rs[n + 1];
  float edv = ed3[n];
  float den = 0.f, a0 = 0.f, a1 = 0.f;
  for (int j = beg; j < end; ++j) {
    int s = esrc[j];
    float e = es3[s] + edv;
    e = e > 0.f ? e : NEG * e;
    float exv = __expf(e);
    den += exv;
    a0 += exv * H3p[2 * s];
    a1 += exv * H3p[2 * s + 1];
  }
  float inv = 1.f / (den + 1e-16f);
  out[2 * n]     = base[2 * n]     + a0 * inv;
  out[2 * n + 1] = base[2 * n + 1] + a1 * inv;
}

extern "C" void kernel_launch(void* const* d_in, const int* in_sizes, int n_in,
                              void* d_out, int out_size, void* d_ws, size_t ws_size,
                              hipStream_t stream) {
  (void)in_sizes; (void)n_in; (void)out_size; (void)ws_size;
  const float* x    = (const float*)d_in[0];
  const int*   ei   = (const int*)d_in[1];
  const float* W1   = (const float*)d_in[2];
  const float* a1s  = (const float*)d_in[3];
  const float* a1d  = (const float*)d_in[4];
  const float* b1   = (const float*)d_in[5];
  const float* W2   = (const float*)d_in[6];
  const float* a2s  = (const float*)d_in[7];
  const float* a2d  = (const float*)d_in[8];
  const float* b2   = (const float*)d_in[9];
  const float* W3   = (const float*)d_in[10];
  const float* a3s  = (const float*)d_in[11];
  const float* a3d  = (const float*)d_in[12];
  const float* b3   = (const float*)d_in[13];
  const float* Wr1  = (const float*)d_in[14];
  const float* Wr2  = (const float*)d_in[15];
  const float* Wsk  = (const float*)d_in[16];
  float* out = (float*)d_out;

  // ---- workspace (~250 MB) ----
  char* w = (char*)d_ws;
  size_t off = 0;
  auto alloc = [&](size_t bytes) { void* p = w + off; off += (bytes + 255) & ~(size_t)255; return p; };
  int* cnt   = (int*)alloc((size_t)NN * 4);
  int* cur   = (int*)alloc((size_t)NN * 4);
  int* rs    = (int*)alloc((size_t)(NN + 1) * 4);
  int* bs    = (int*)alloc(256 * 4);
  int* esrc  = (int*)alloc((size_t)ETOT * 4);
  float* es  = (float*)alloc((size_t)MPAD * HEADS * 4);
  float* ed  = (float*)alloc((size_t)MPAD * HEADS * 4);
  u16* W1t   = (u16*)alloc((size_t)NP1 * KP1 * 2);
  u16* W2t   = (u16*)alloc((size_t)NP2 * DIM * 2);
  float* H3p = (float*)alloc((size_t)NN * 2 * 4);
  float* base= (float*)alloc((size_t)NN * 2 * 4);
  float* es3 = (float*)alloc((size_t)NN * 4);
  float* ed3 = (float*)alloc((size_t)NN * 4);
  float* skp = (float*)alloc((size_t)NN * 2 * 4);
  u16* bufB  = (u16*)alloc((size_t)MPAD * DIM * 2);    // h1bf (GEMM2 A)
  u16* bufA  = (u16*)alloc((size_t)MPAD * DIM2 * 2);   // H1p, later G2 (fused proj|resid)
  u16* H1p   = bufA;
  u16* G2    = bufA;
  u16* A1    = bufA + (size_t)MPAD * DIM;              // alias upper half of bufA (dead before G2)

  const int nb = (NN + 255) / 256;        // 196
  const int ge = (ETOT + 255) / 256;      // 977

  // CSR build
  hipMemsetAsync(cnt, 0, (size_t)NN * 4, stream);
  hipMemsetAsync(cur, 0, (size_t)NN * 4, stream);
  k_count<<<ge, 256, 0, stream>>>(ei, cnt);
  k_bsum <<<nb, 256, 0, stream>>>(cnt, bs);
  k_top  <<<1, 256, 0, stream>>>(bs, rs, nb);
  k_scan <<<nb, 256, 0, stream>>>(cnt, bs, rs);
  k_fill <<<ge, 256, 0, stream>>>(ei, rs, cur, esrc);

  // converts (+ fused es/ed weight columns) + x@Wskip
  k_cvt_x <<<(MPAD * KP1) / 256, 256, 0, stream>>>(x, A1);
  k_cvt_w1<<<(NP1 * KP1) / 256, 256, 0, stream>>>(W1, W1t);
  k_wa    <<<(16 * KP1 + 255) / 256, 256, 0, stream>>>(W1, a1s, a1d, W1t, FIN, KP1, DIM);
  k_cvt_w2<<<(NP2 * DIM) / 256, 256, 0, stream>>>(W2, Wr1, W2t);
  k_wa    <<<(16 * DIM + 255) / 256, 256, 0, stream>>>(W2, a2s, a2d, W2t, DIM, DIM, DIM2);
  k_l3x   <<<(NN + 3) / 4, 256, 0, stream>>>(x, Wsk, skp);

  // layer 1 (GEMM also emits es/ed via fused columns 800-815)
  k_gemm<<<dim3(NP1 / 128, MPAD / 128), 256, 0, stream>>>(A1, W1t, H1p, es, ed,
                                                          KP1 / 32, KP1, DIM, DIM + 16, DIM);
  k_agg1<<<NN, 256, 0, stream>>>(rs, esrc, H1p, es, ed, b1, bufB);

  // layer 2 (W2|Wres1 fused GEMM; es/ed via fused columns 1600-1615)
  k_gemm<<<dim3(NP2 / 128, MPAD / 128), 256, 0, stream>>>(bufB, W2t, G2, es, ed,
                                                          DIM / 32, DIM, DIM2, DIM2 + 16, DIM2);
  k_agg2f<<<NN, 256, 0, stream>>>(rs, esrc, G2, es, ed, b2, G2 + DIM,
                                  W3, Wr2, a3s, a3d, b3, skp, H3p, base, es3, ed3);

  // layer 3 softmax-aggregate
  k_l3agg<<<nb, 256, 0, stream>>>(rs, esrc, H3p, base, es3, ed3, out);
}

// Round 12
// 480.860 us; speedup vs baseline: 1.2426x; 1.0569x over previous
//
#include <hip/hip_runtime.h>

#define NN     50000
#define NE     200000
#define ETOT   250000   // NE + NN self-loops
#define FIN    165
#define KP1    192      // FIN padded to mult of 32
#define HEADS  8
#define CH     100
#define DIM    800      // 8*100
#define MPAD   50048    // 391*128
#define NP1    896      // 7*128  (pad of 816: 800 data + 16 es/ed)
#define DIM2   1600     // W2|Wres1 fused output
#define NP2    1664     // 13*128 (pad of 1616: 1600 data + 16 es/ed)
#define NEG    0.2f
#define CHK    64       // agg softmax chunk (LDS ex buffer = CHK*8 floats)

typedef unsigned short u16;
typedef unsigned int   u32;
typedef __bf16 bf16x8 __attribute__((ext_vector_type(8)));
typedef float  f32x4  __attribute__((ext_vector_type(4)));

__device__ __forceinline__ u16 f2b(float f) {
  u32 u = __float_as_uint(f);
  u = (u + 0x7FFFu + ((u >> 16) & 1u)) >> 16;   // RNE
  return (u16)u;
}
__device__ __forceinline__ float b2f(u16 u) { return __uint_as_float(((u32)u) << 16); }

// ---------------- CSR build (dst -> list of src), reused by all 3 layers ----------------
__global__ void k_count(const int* __restrict__ ei, int* __restrict__ cnt) {
  int e = blockIdx.x * 256 + threadIdx.x;
  if (e >= ETOT) return;
  int d = (e < NE) ? ei[NE + e] : (e - NE);
  atomicAdd(&cnt[d], 1);
}
__global__ void k_bsum(const int* __restrict__ cnt, int* __restrict__ bs) {
  __shared__ int sm[256];
  int i = blockIdx.x * 256 + threadIdx.x;
  sm[threadIdx.x] = (i < NN) ? cnt[i] : 0;
  __syncthreads();
  for (int off = 128; off; off >>= 1) {
    if (threadIdx.x < off) sm[threadIdx.x] += sm[threadIdx.x + off];
    __syncthreads();
  }
  if (!threadIdx.x) bs[blockIdx.x] = sm[0];
}
__global__ void k_top(int* __restrict__ bs, int* __restrict__ rs, int nb) {
  __shared__ int sm[256];
  int t = threadIdx.x;
  int v = (t < nb) ? bs[t] : 0;
  sm[t] = v; __syncthreads();
  for (int off = 1; off < 256; off <<= 1) {
    int add = (t >= off) ? sm[t - off] : 0;
    __syncthreads();
    sm[t] += add;
    __syncthreads();
  }
  if (t < nb) bs[t] = sm[t] - v;   // exclusive block offsets
  if (!t) rs[NN] = ETOT;
}
__global__ void k_scan(const int* __restrict__ cnt, const int* __restrict__ bs, int* __restrict__ rs) {
  __shared__ int sm[256];
  int t = threadIdx.x, i = blockIdx.x * 256 + t;
  int v = (i < NN) ? cnt[i] : 0;
  sm[t] = v; __syncthreads();
  for (int off = 1; off < 256; off <<= 1) {
    int add = (t >= off) ? sm[t - off] : 0;
    __syncthreads();
    sm[t] += add;
    __syncthreads();
  }
  if (i < NN) rs[i] = bs[blockIdx.x] + sm[t] - v;
}
__global__ void k_fill(const int* __restrict__ ei, const int* __restrict__ rs,
                       int* __restrict__ cur, int* __restrict__ esrc) {
  int e = blockIdx.x * 256 + threadIdx.x;
  if (e >= ETOT) return;
  int s, d;
  if (e < NE) { s = ei[e]; d = ei[NE + e]; } else { s = d = e - NE; }
  int pos = atomicAdd(&cur[d], 1);
  esrc[rs[d] + pos] = s;
}

// ==== fused prep: converts + fused-attention weight cols + x@Wskip + zero cnt/cur ====
// Block ranges: [0,37536) cvt_x | [37536,38208) cvt_w1 | [38208,38220) wa1 |
// [38220,43420) cvt_w2 | [43420,43470) wa2 | [43470,55970) l3x | [55970,56361) zero
#define PR_X   37536
#define PR_W1  38208
#define PR_WA1 38220
#define PR_W2  43420
#define PR_WA2 43470
#define PR_L3X 55970
#define PR_Z   56361

__device__ __forceinline__ void d_wa(int idx, const float* W, const float* as,
                                     const float* ad, u16* Wt, int Kin, int Kpad, int Dsp) {
  int j = idx / Kpad, k = idx - j * Kpad;
  int h = j & 7;
  const float* a = ((j < 8) ? as : ad) + h * CH;
  float s = 0.f;
  if (k < Kin) {
    const float* wr = W + (size_t)k * DIM + h * CH;
    for (int c = 0; c < CH; ++c) s += wr[c] * a[c];
  }
  Wt[(size_t)(Dsp + j) * Kpad + k] = f2b(s);
}

__global__ __launch_bounds__(256) void k_prep(const float* __restrict__ x,
    const float* __restrict__ W1, const float* __restrict__ a1s, const float* __restrict__ a1d,
    const float* __restrict__ W2, const float* __restrict__ Wr1,
    const float* __restrict__ a2s, const float* __restrict__ a2d,
    const float* __restrict__ Wsk,
    u16* __restrict__ A1, u16* __restrict__ W1t, u16* __restrict__ W2t,
    float* __restrict__ skp, int* __restrict__ cnt, int* __restrict__ cur) {
  int b = blockIdx.x, t = threadIdx.x;
  if (b < PR_X) {                      // x -> bf16 padded [MPAD][KP1]
    int idx = b * 256 + t;
    int r = idx / KP1, k = idx - r * KP1;
    float v = (r < NN && k < FIN) ? x[r * FIN + k] : 0.f;
    A1[idx] = f2b(v);
  } else if (b < PR_W1) {              // W1^T bf16 [NP1][KP1] (rows < DIM)
    int idx = (b - PR_X) * 256 + t;
    int j = idx / KP1, k = idx - j * KP1;
    float v = (j < DIM && k < FIN) ? W1[k * DIM + j] : 0.f;
    W1t[idx] = f2b(v);
  } else if (b < PR_WA1) {             // fused es/ed cols for layer 1
    int idx = (b - PR_W1) * 256 + t;
    d_wa(idx, W1, a1s, a1d, W1t, FIN, KP1, DIM);
  } else if (b < PR_W2) {              // [W2|Wres1]^T bf16 [NP2][DIM]
    int idx = (b - PR_WA1) * 256 + t;
    int j = idx / DIM, k = idx - j * DIM;
    float v = 0.f;
    if (j < DIM) v = W2[k * DIM + j];
    else if (j < 2 * DIM) v = Wr1[k * DIM + (j - DIM)];
    W2t[idx] = f2b(v);
  } else if (b < PR_WA2) {             // fused es/ed cols for layer 2
    int idx = (b - PR_W2) * 256 + t;
    d_wa(idx, W2, a2s, a2d, W2t, DIM, DIM, DIM2);
  } else if (b < PR_L3X) {             // x @ Wskip (one wave per node)
    int wv = t >> 6, lane = t & 63;
    int n = (b - PR_WA2) * 4 + wv;
    if (n >= NN) return;
    float s0 = 0.f, s1 = 0.f;
    const float* xr = x + (size_t)n * FIN;
    for (int c = lane; c < FIN; c += 64) {
      float v = xr[c];
      s0 += v * Wsk[2 * c]; s1 += v * Wsk[2 * c + 1];
    }
#pragma unroll
    for (int off = 32; off; off >>= 1) {
      s0 += __shfl_down(s0, off); s1 += __shfl_down(s1, off);
    }
    if (!lane) { skp[2 * n] = s0; skp[2 * n + 1] = s1; }
  } else {                             // zero cnt + cur
    int i = (b - PR_L3X) * 256 + t;
    if (i < NN) cnt[i] = 0;
    else if (i < 2 * NN) cur[i - NN] = 0;
  }
}

// ---------------- bf16 MFMA GEMM: 128^2 tile, BK=32, 2-phase dbuf ----------------
// LDS layout (R7-proven, 0 bank conflicts): 8 subtiles of [16 rows][32 k] per
// 128x32 tile; within a subtile, k-block stored at col = k ^ ((row_in>>3)&1)*16.
// gload_lds dest stays LINEAR (chunk*16B); the GLOBAL source applies the inverse
// permutation; the ds_read applies the same XOR (rule #21 both-sides).
__device__ __forceinline__ void gl_lds16(const u16* g, u16* l) {
  __builtin_amdgcn_global_load_lds((const __attribute__((address_space(1))) void*)g,
                                   (__attribute__((address_space(3))) void*)l, 16, 0, 0);
}

__global__ __launch_bounds__(256) void k_gemm(const u16* __restrict__ A, const u16* __restrict__ Bt,
                                              u16* __restrict__ C, float* __restrict__ es,
                                              float* __restrict__ ed, int ksteps, int K,
                                              int Dsplit, int Nreal, int ldC) {
  __shared__ __align__(16) u16 lA[2][128 * 32];
  __shared__ __align__(16) u16 lB[2][128 * 32];
  int t = threadIdx.x;
  int lane = t & 63, wv = t >> 6;

  // T1 XCD swizzle (bijective chunked, m204)
  int nwg = gridDim.x * gridDim.y;
  int h = blockIdx.y * gridDim.x + blockIdx.x;
  int q = nwg >> 3, r8 = nwg & 7;
  int xcd = h & 7, i8 = h >> 3;
  int ln = (xcd < r8 ? xcd * (q + 1) : r8 * (q + 1) + (xcd - r8) * q) + i8;
  int tn = (ln % gridDim.x) * 128, tm = (ln / gridDim.x) * 128;

  int wr = (wv >> 1) * 64, wc = (wv & 1) * 64;
  int rl = lane & 15, kl = (lane >> 4) * 8;
  int rdo = rl * 32 + (kl ^ (((rl >> 3) & 1) << 4));   // subtile-relative read offset

  f32x4 acc[4][4];
#pragma unroll
  for (int i = 0; i < 4; ++i)
#pragma unroll
    for (int j = 0; j < 4; ++j) acc[i][j] = (f32x4){0.f, 0.f, 0.f, 0.f};

  auto stage = [&](int buf, int ks) {
    int k0 = ks * 32;
#pragma unroll
    for (int r = 0; r < 2; ++r) {
      int chunk = r * 256 + t;
      int row = ((chunk >> 6) << 4) + ((chunk >> 2) & 15);          // subtile*16 + row_in
      int kb  = ((chunk & 3) << 3) ^ (((chunk >> 5) & 1) << 4);     // inverse XOR on source
      gl_lds16(A + (size_t)(tm + row) * K + k0 + kb, &lA[buf][chunk * 8]);
      gl_lds16(Bt + (size_t)(tn + row) * K + k0 + kb, &lB[buf][chunk * 8]);
    }
  };

  stage(0, 0);
  int cur = 0;
  for (int ks = 0; ks < ksteps; ++ks) {
    __syncthreads();                       // drains vmcnt(0): buf[cur] fully written
    if (ks + 1 < ksteps) stage(cur ^ 1, ks + 1);   // loads fly under the MFMAs below
    bf16x8 af[4], bfr[4];
#pragma unroll
    for (int i = 0; i < 4; ++i) {
      af[i]  = *(const bf16x8*)&lA[cur][(((wr + i * 16) >> 4) << 9) + rdo];
      bfr[i] = *(const bf16x8*)&lB[cur][(((wc + i * 16) >> 4) << 9) + rdo];
    }
#pragma unroll
    for (int i = 0; i < 4; ++i)
#pragma unroll
      for (int j = 0; j < 4; ++j)
        acc[i][j] = __builtin_amdgcn_mfma_f32_16x16x32_bf16(af[i], bfr[j], acc[i][j], 0, 0, 0);
    cur ^= 1;
  }
  int rq = (lane >> 4) * 4;
#pragma unroll
  for (int i = 0; i < 4; ++i) {
#pragma unroll
    for (int j = 0; j < 4; ++j) {
      int col = tn + wc + j * 16 + rl;
      if (col < Dsplit) {
#pragma unroll
        for (int q2 = 0; q2 < 4; ++q2) {
          int row = tm + wr + i * 16 + rq + q2;
          C[(size_t)row * ldC + col] = f2b(acc[i][j][q2]);
        }
      } else if (col < Nreal) {
        int cj = col - Dsplit;
        float* dst = (cj < 8) ? es : ed;
        int hh = cj & 7;
#pragma unroll
        for (int q2 = 0; q2 < 4; ++q2) {
          int row = tm + wr + i * 16 + rq + q2;
          dst[(size_t)row * 8 + hh] = acc[i][j][q2];
        }
      }
    }
  }
}

// ==== fused softmax-stats + aggregation (chunked in-LDS, R11-proven) ====

// ---- layer-1: writes h1 (GEMM2 A-matrix) ----
__global__ __launch_bounds__(256) void k_agg1(const int* __restrict__ rs, const int* __restrict__ esrc,
    const u16* __restrict__ Hp, const float* __restrict__ es, const float* __restrict__ ed,
    const float* __restrict__ bias, u16* __restrict__ out) {
  __shared__ float sm_ex[CHK * 8];
  __shared__ float sm_den[8];
  __shared__ int   sm_src[CHK];
  int n = blockIdx.x, t = threadIdx.x;
  if (t < 8) sm_den[t] = 0.f;
  int beg = rs[n], end = rs[n + 1];
  int c = t * 4;
  int h = t / 25;
  float a0 = 0.f, a1 = 0.f, a2 = 0.f, a3 = 0.f;
  __syncthreads();
  for (int ch = beg; ch < end; ch += CHK) {
    int ce = min(end, ch + CHK);
    int m = ce - ch;
    if (t < m) sm_src[t] = esrc[ch + t];
    __syncthreads();
    for (int i = t; i < m * 8; i += 256) {
      int e8 = i >> 3, hh = i & 7;
      float xv = es[sm_src[e8] * 8 + hh] + ed[n * 8 + hh];
      xv = xv > 0.f ? xv : NEG * xv;
      float e = __expf(xv);
      sm_ex[i] = e;
      atomicAdd(&sm_den[hh], e);
    }
    __syncthreads();
    if (t < 200) {
      for (int j = 0; j < m; ++j) {
        float w = sm_ex[j * 8 + h];
        ushort4 u = *(const ushort4*)(Hp + (size_t)sm_src[j] * DIM + c);
        a0 += w * b2f(u.x); a1 += w * b2f(u.y); a2 += w * b2f(u.z); a3 += w * b2f(u.w);
      }
    }
    __syncthreads();
  }
  if (t >= 200) return;
  float inv = 1.f / (sm_den[h] + 1e-16f);
  const float4 bb = *(const float4*)(bias + c);
  float v0 = a0 * inv + bb.x, v1 = a1 * inv + bb.y, v2 = a2 * inv + bb.z, v3 = a3 * inv + bb.w;
  v0 = v0 > 0.f ? v0 : __expf(v0) - 1.f;
  v1 = v1 > 0.f ? v1 : __expf(v1) - 1.f;
  v2 = v2 > 0.f ? v2 : __expf(v2) - 1.f;
  v3 = v3 > 0.f ? v3 : __expf(v3) - 1.f;
  ushort4 o;
  o.x = f2b(v0); o.y = f2b(v1); o.z = f2b(v2); o.w = f2b(v3);
  *(ushort4*)(out + (size_t)n * DIM + c) = o;
}

// ---- layer-2: fused stats + agg + resid + ELU + layer-3 skinny projections ----
__global__ __launch_bounds__(256) void k_agg2f(const int* __restrict__ rs, const int* __restrict__ esrc,
    const u16* __restrict__ Hp, const float* __restrict__ es, const float* __restrict__ ed,
    const float* __restrict__ bias, const u16* __restrict__ resid,
    const float* __restrict__ W3, const float* __restrict__ Wres2,
    const float* __restrict__ a3s, const float* __restrict__ a3d, const float* __restrict__ b3,
    const float* __restrict__ skp,
    float* __restrict__ H3p, float* __restrict__ base,
    float* __restrict__ es3, float* __restrict__ ed3) {
  __shared__ float sm_ex[CHK * 8];
  __shared__ float sm_den[8];
  __shared__ int   sm_src[CHK];
  __shared__ float red[4][4];
  int n = blockIdx.x, t = threadIdx.x;
  int lane = t & 63, wv = t >> 6;
  if (t < 8) sm_den[t] = 0.f;
  int beg = rs[n], end = rs[n + 1];
  int c = t * 4;
  int h = t / 25;
  float a0 = 0.f, a1 = 0.f, a2 = 0.f, a3 = 0.f;
  __syncthreads();
  for (int ch = beg; ch < end; ch += CHK) {
    int ce = min(end, ch + CHK);
    int m = ce - ch;
    if (t < m) sm_src[t] = esrc[ch + t];
    __syncthreads();
    for (int i = t; i < m * 8; i += 256) {
      int e8 = i >> 3, hh = i & 7;
      float xv = es[sm_src[e8] * 8 + hh] + ed[n * 8 + hh];
      xv = xv > 0.f ? xv : NEG * xv;
      float e = __expf(xv);
      sm_ex[i] = e;
      atomicAdd(&sm_den[hh], e);
    }
    __syncthreads();
    if (t < 200) {
      for (int j = 0; j < m; ++j) {
        float w = sm_ex[j * 8 + h];
        ushort4 u = *(const ushort4*)(Hp + (size_t)sm_src[j] * DIM2 + c);
        a0 += w * b2f(u.x); a1 += w * b2f(u.y); a2 += w * b2f(u.z); a3 += w * b2f(u.w);
      }
    }
    __syncthreads();
  }
  float p0 = 0.f, p1 = 0.f, r0 = 0.f, r1 = 0.f;
  if (t < 200) {
    float inv = 1.f / (sm_den[h] + 1e-16f);
    const float4 bb = *(const float4*)(bias + c);
    ushort4 rr = *(const ushort4*)(resid + (size_t)n * DIM2 + c);
    float v0 = a0 * inv + bb.x + b2f(rr.x);
    float v1 = a1 * inv + bb.y + b2f(rr.y);
    float v2 = a2 * inv + bb.z + b2f(rr.z);
    float v3 = a3 * inv + bb.w + b2f(rr.w);
    v0 = v0 > 0.f ? v0 : __expf(v0) - 1.f;
    v1 = v1 > 0.f ? v1 : __expf(v1) - 1.f;
    v2 = v2 > 0.f ? v2 : __expf(v2) - 1.f;
    v3 = v3 > 0.f ? v3 : __expf(v3) - 1.f;
    const float4 w3a = *(const float4*)(W3 + 2 * c);
    const float4 w3b = *(const float4*)(W3 + 2 * c + 4);
    const float4 wra = *(const float4*)(Wres2 + 2 * c);
    const float4 wrb = *(const float4*)(Wres2 + 2 * c + 4);
    p0 = v0 * w3a.x + v1 * w3a.z + v2 * w3b.x + v3 * w3b.z;
    p1 = v0 * w3a.y + v1 * w3a.w + v2 * w3b.y + v3 * w3b.w;
    r0 = v0 * wra.x + v1 * wra.z + v2 * wrb.x + v3 * wrb.z;
    r1 = v0 * wra.y + v1 * wra.w + v2 * wrb.y + v3 * wrb.w;
  }
#pragma unroll
  for (int off = 32; off; off >>= 1) {
    p0 += __shfl_down(p0, off); p1 += __shfl_down(p1, off);
    r0 += __shfl_down(r0, off); r1 += __shfl_down(r1, off);
  }
  if (!lane) { red[wv][0] = p0; red[wv][1] = p1; red[wv][2] = r0; red[wv][3] = r1; }
  __syncthreads();
  if (!t) {
    float P0 = red[0][0] + red[1][0] + red[2][0] + red[3][0];
    float P1 = red[0][1] + red[1][1] + red[2][1] + red[3][1];
    float R0 = red[0][2] + red[1][2] + red[2][2] + red[3][2];
    float R1 = red[0][3] + red[1][3] + red[2][3] + red[3][3];
    H3p[2 * n] = P0; H3p[2 * n + 1] = P1;
    es3[n] = P0 * a3s[0] + P1 * a3s[1];
    ed3[n] = P0 * a3d[0] + P1 * a3d[1];
    base[2 * n]     = R0 + skp[2 * n]     + b3[0];
    base[2 * n + 1] = R1 + skp[2 * n + 1] + b3[1];
  }
}

// ---------------- layer 3 softmax+aggregate (1 head, 2 ch) -> final logits ----------------
__global__ void k_l3agg(const int* __restrict__ rs, const int* __restrict__ esrc,
                        const float* __restrict__ H3p, const float* __restrict__ base,
                        const float* __restrict__ es3, const float* __restrict__ ed3,
                        float* __restrict__ out) {
  int n = blockIdx.x * 256 + threadIdx.x;
  if (n >= NN) return;
  int beg = rs[n], end = rs[n + 1];
  float edv = ed3[n];
  float den = 0.f, a0 = 0.f, a1 = 0.f;
  for (int j = beg; j < end; ++j) {
    int s = esrc[j];
    float e = es3[s] + edv;
    e = e > 0.f ? e : NEG * e;
    float exv = __expf(e);
    den += exv;
    a0 += exv * H3p[2 * s];
    a1 += exv * H3p[2 * s + 1];
  }
  float inv = 1.f / (den + 1e-16f);
  out[2 * n]     = base[2 * n]     + a0 * inv;
  out[2 * n + 1] = base[2 * n + 1] + a1 * inv;
}

extern "C" void kernel_launch(void* const* d_in, const int* in_sizes, int n_in,
                              void* d_out, int out_size, void* d_ws, size_t ws_size,
                              hipStream_t stream) {
  (void)in_sizes; (void)n_in; (void)out_size; (void)ws_size;
  const float* x    = (const float*)d_in[0];
  const int*   ei   = (const int*)d_in[1];
  const float* W1   = (const float*)d_in[2];
  const float* a1s  = (const float*)d_in[3];
  const float* a1d  = (const float*)d_in[4];
  const float* b1   = (const float*)d_in[5];
  const float* W2   = (const float*)d_in[6];
  const float* a2s  = (const float*)d_in[7];
  const float* a2d  = (const float*)d_in[8];
  const float* b2   = (const float*)d_in[9];
  const float* W3   = (const float*)d_in[10];
  const float* a3s  = (const float*)d_in[11];
  const float* a3d  = (const float*)d_in[12];
  const float* b3   = (const float*)d_in[13];
  const float* Wr1  = (const float*)d_in[14];
  const float* Wr2  = (const float*)d_in[15];
  const float* Wsk  = (const float*)d_in[16];
  float* out = (float*)d_out;

  // ---- workspace (~250 MB) ----
  char* w = (char*)d_ws;
  size_t off = 0;
  auto alloc = [&](size_t bytes) { void* p = w + off; off += (bytes + 255) & ~(size_t)255; return p; };
  int* cnt   = (int*)alloc((size_t)NN * 4);
  int* cur   = (int*)alloc((size_t)NN * 4);
  int* rs    = (int*)alloc((size_t)(NN + 1) * 4);
  int* bs    = (int*)alloc(256 * 4);
  int* esrc  = (int*)alloc((size_t)ETOT * 4);
  float* es  = (float*)alloc((size_t)MPAD * HEADS * 4);
  float* ed  = (float*)alloc((size_t)MPAD * HEADS * 4);
  u16* W1t   = (u16*)alloc((size_t)NP1 * KP1 * 2);
  u16* W2t   = (u16*)alloc((size_t)NP2 * DIM * 2);
  float* H3p = (float*)alloc((size_t)NN * 2 * 4);
  float* base= (float*)alloc((size_t)NN * 2 * 4);
  float* es3 = (float*)alloc((size_t)NN * 4);
  float* ed3 = (float*)alloc((size_t)NN * 4);
  float* skp = (float*)alloc((size_t)NN * 2 * 4);
  u16* bufB  = (u16*)alloc((size_t)MPAD * DIM * 2);    // h1bf (GEMM2 A)
  u16* bufA  = (u16*)alloc((size_t)MPAD * DIM2 * 2);   // H1p, later G2 (fused proj|resid)
  u16* H1p   = bufA;
  u16* G2    = bufA;
  u16* A1    = bufA + (size_t)MPAD * DIM;              // alias upper half of bufA (dead before G2)

  const int nb = (NN + 255) / 256;        // 196
  const int ge = (ETOT + 255) / 256;      // 977

  // fused prep (includes zeroing cnt/cur for the CSR build)
  k_prep<<<PR_Z, 256, 0, stream>>>(x, W1, a1s, a1d, W2, Wr1, a2s, a2d, Wsk,
                                   A1, W1t, W2t, skp, cnt, cur);

  // CSR build
  k_count<<<ge, 256, 0, stream>>>(ei, cnt);
  k_bsum <<<nb, 256, 0, stream>>>(cnt, bs);
  k_top  <<<1, 256, 0, stream>>>(bs, rs, nb);
  k_scan <<<nb, 256, 0, stream>>>(cnt, bs, rs);
  k_fill <<<ge, 256, 0, stream>>>(ei, rs, cur, esrc);

  // layer 1 (GEMM also emits es/ed via fused columns 800-815)
  k_gemm<<<dim3(NP1 / 128, MPAD / 128), 256, 0, stream>>>(A1, W1t, H1p, es, ed,
                                                          KP1 / 32, KP1, DIM, DIM + 16, DIM);
  k_agg1<<<NN, 256, 0, stream>>>(rs, esrc, H1p, es, ed, b1, bufB);

  // layer 2 (W2|Wres1 fused GEMM; es/ed via fused columns 1600-1615)
  k_gemm<<<dim3(NP2 / 128, MPAD / 128), 256, 0, stream>>>(bufB, W2t, G2, es, ed,
                                                          DIM / 32, DIM, DIM2, DIM2 + 16, DIM2);
  k_agg2f<<<NN, 256, 0, stream>>>(rs, esrc, G2, es, ed, b2, G2 + DIM,
                                  W3, Wr2, a3s, a3d, b3, skp, H3p, base, es3, ed3);

  // layer 3 softmax-aggregate
  k_l3agg<<<nb, 256, 0, stream>>>(rs, esrc, H3p, base, es3, ed3, out);
}

// Round 13
// 479.818 us; speedup vs baseline: 1.2453x; 1.0022x over previous
//
#include <hip/hip_runtime.h>

#define NN     50000
#define NE     200000
#define ETOT   250000   // NE + NN self-loops
#define FIN    165
#define KP1    192      // FIN padded to mult of 32
#define HEADS  8
#define CH     100
#define DIM    800      // 8*100
#define MPAD   50048    // 391*128
#define NP1    896      // 7*128  (pad of 816: 800 data + 16 es/ed)
#define DIM2   1600     // W2|Wres1 fused output
#define NP2    1664     // 13*128 (pad of 1616: 1600 data + 16 es/ed)
#define NEG    0.2f
#define CHK    64       // agg softmax chunk (LDS ex buffer = CHK*8 floats)

typedef unsigned short u16;
typedef unsigned int   u32;
typedef __bf16 bf16x8 __attribute__((ext_vector_type(8)));
typedef float  f32x4  __attribute__((ext_vector_type(4)));

__device__ __forceinline__ u16 f2b(float f) {
  u32 u = __float_as_uint(f);
  u = (u + 0x7FFFu + ((u >> 16) & 1u)) >> 16;   // RNE
  return (u16)u;
}
__device__ __forceinline__ float b2f(u16 u) { return __uint_as_float(((u32)u) << 16); }

// ---------------- CSR build (dst -> list of src), reused by all 3 layers ----------------
__global__ void k_count(const int* __restrict__ ei, int* __restrict__ cnt) {
  int e = blockIdx.x * 256 + threadIdx.x;
  if (e >= ETOT) return;
  int d = (e < NE) ? ei[NE + e] : (e - NE);
  atomicAdd(&cnt[d], 1);
}
__global__ void k_bsum(const int* __restrict__ cnt, int* __restrict__ bs) {
  __shared__ int sm[256];
  int i = blockIdx.x * 256 + threadIdx.x;
  sm[threadIdx.x] = (i < NN) ? cnt[i] : 0;
  __syncthreads();
  for (int off = 128; off; off >>= 1) {
    if (threadIdx.x < off) sm[threadIdx.x] += sm[threadIdx.x + off];
    __syncthreads();
  }
  if (!threadIdx.x) bs[blockIdx.x] = sm[0];
}
__global__ void k_top(int* __restrict__ bs, int* __restrict__ rs, int nb) {
  __shared__ int sm[256];
  int t = threadIdx.x;
  int v = (t < nb) ? bs[t] : 0;
  sm[t] = v; __syncthreads();
  for (int off = 1; off < 256; off <<= 1) {
    int add = (t >= off) ? sm[t - off] : 0;
    __syncthreads();
    sm[t] += add;
    __syncthreads();
  }
  if (t < nb) bs[t] = sm[t] - v;   // exclusive block offsets
  if (!t) rs[NN] = ETOT;
}
__global__ void k_scan(const int* __restrict__ cnt, const int* __restrict__ bs, int* __restrict__ rs) {
  __shared__ int sm[256];
  int t = threadIdx.x, i = blockIdx.x * 256 + t;
  int v = (i < NN) ? cnt[i] : 0;
  sm[t] = v; __syncthreads();
  for (int off = 1; off < 256; off <<= 1) {
    int add = (t >= off) ? sm[t - off] : 0;
    __syncthreads();
    sm[t] += add;
    __syncthreads();
  }
  if (i < NN) rs[i] = bs[blockIdx.x] + sm[t] - v;
}
__global__ void k_fill(const int* __restrict__ ei, const int* __restrict__ rs,
                       int* __restrict__ cur, int* __restrict__ esrc) {
  int e = blockIdx.x * 256 + threadIdx.x;
  if (e >= ETOT) return;
  int s, d;
  if (e < NE) { s = ei[e]; d = ei[NE + e]; } else { s = d = e - NE; }
  int pos = atomicAdd(&cur[d], 1);
  esrc[rs[d] + pos] = s;
}

// ==== fused prep: converts + fused-attention weight cols + x@Wskip + zero cnt/cur ====
// Block ranges (cvt_x vectorized x4):
#define PR_X   9384    // MPAD*KP1/4/256
#define PR_W1  10056   // + NP1*KP1/256 (672)
#define PR_WA1 10068   // + 16*KP1/256 (12)
#define PR_W2  15268   // + NP2*DIM/256 (5200)
#define PR_WA2 15318   // + 16*DIM/256 (50)
#define PR_L3X 27818   // + (NN+3)/4 (12500)
#define PR_Z   28209   // + ceil(2*NN/256) (391)

__device__ __forceinline__ void d_wa(int idx, const float* W, const float* as,
                                     const float* ad, u16* Wt, int Kin, int Kpad, int Dsp) {
  int j = idx / Kpad, k = idx - j * Kpad;
  int h = j & 7;
  const float* a = ((j < 8) ? as : ad) + h * CH;
  float s = 0.f;
  if (k < Kin) {
    const float* wr = W + (size_t)k * DIM + h * CH;
    for (int c = 0; c < CH; ++c) s += wr[c] * a[c];
  }
  Wt[(size_t)(Dsp + j) * Kpad + k] = f2b(s);
}

__global__ __launch_bounds__(256) void k_prep(const float* __restrict__ x,
    const float* __restrict__ W1, const float* __restrict__ a1s, const float* __restrict__ a1d,
    const float* __restrict__ W2, const float* __restrict__ Wr1,
    const float* __restrict__ a2s, const float* __restrict__ a2d,
    const float* __restrict__ Wsk,
    u16* __restrict__ A1, u16* __restrict__ W1t, u16* __restrict__ W2t,
    float* __restrict__ skp, int* __restrict__ cnt, int* __restrict__ cur) {
  int b = blockIdx.x, t = threadIdx.x;
  if (b < PR_X) {                      // x -> bf16 padded [MPAD][KP1], 4 elems/thread
    int idx4 = b * 256 + t;
    int r = idx4 / 48;                 // KP1/4 = 48
    int kq = (idx4 - r * 48) * 4;
    ushort4 o = (ushort4){0, 0, 0, 0};
    if (r < NN) {
      const float* xr = x + (size_t)r * FIN;
      float v0 = (kq + 0 < FIN) ? xr[kq + 0] : 0.f;
      float v1 = (kq + 1 < FIN) ? xr[kq + 1] : 0.f;
      float v2 = (kq + 2 < FIN) ? xr[kq + 2] : 0.f;
      float v3 = (kq + 3 < FIN) ? xr[kq + 3] : 0.f;
      o.x = f2b(v0); o.y = f2b(v1); o.z = f2b(v2); o.w = f2b(v3);
    }
    *(ushort4*)(A1 + (size_t)r * KP1 + kq) = o;
  } else if (b < PR_W1) {              // W1^T bf16 [NP1][KP1] (zero pad rows)
    int idx = (b - PR_X) * 256 + t;
    int j = idx / KP1, k = idx - j * KP1;
    float v = (j < DIM && k < FIN) ? W1[k * DIM + j] : 0.f;
    W1t[idx] = f2b(v);
  } else if (b < PR_WA1) {             // fused es/ed cols for layer 1
    int idx = (b - PR_W1) * 256 + t;
    d_wa(idx, W1, a1s, a1d, W1t, FIN, KP1, DIM);
  } else if (b < PR_W2) {              // [W2|Wres1]^T bf16 [NP2][DIM]
    int idx = (b - PR_WA1) * 256 + t;
    int j = idx / DIM, k = idx - j * DIM;
    float v = 0.f;
    if (j < DIM) v = W2[k * DIM + j];
    else if (j < 2 * DIM) v = Wr1[k * DIM + (j - DIM)];
    W2t[idx] = f2b(v);
  } else if (b < PR_WA2) {             // fused es/ed cols for layer 2
    int idx = (b - PR_W2) * 256 + t;
    d_wa(idx, W2, a2s, a2d, W2t, DIM, DIM, DIM2);
  } else if (b < PR_L3X) {             // x @ Wskip (one wave per node)
    int wv = t >> 6, lane = t & 63;
    int n = (b - PR_WA2) * 4 + wv;
    if (n >= NN) return;
    float s0 = 0.f, s1 = 0.f;
    const float* xr = x + (size_t)n * FIN;
    for (int c = lane; c < FIN; c += 64) {
      float v = xr[c];
      s0 += v * Wsk[2 * c]; s1 += v * Wsk[2 * c + 1];
    }
#pragma unroll
    for (int off = 32; off; off >>= 1) {
      s0 += __shfl_down(s0, off); s1 += __shfl_down(s1, off);
    }
    if (!lane) { skp[2 * n] = s0; skp[2 * n + 1] = s1; }
  } else {                             // zero cnt + cur
    int i = (b - PR_L3X) * 256 + t;
    if (i < NN) cnt[i] = 0;
    else if (i < 2 * NN) cur[i - NN] = 0;
  }
}

// ---------------- bf16 MFMA GEMM: 128^2 tile, BK=32, 2-phase dbuf ----------------
// LDS layout (R12-proven, 0 bank conflicts): 8 subtiles of [16 rows][32 k];
// within a subtile, k-block stored at col = k ^ ((row_in>>3)&1)*16.
// gload_lds dest LINEAR; GLOBAL source inverse-permuted; ds_read same XOR.
__device__ __forceinline__ void gl_lds16(const u16* g, u16* l) {
  __builtin_amdgcn_global_load_lds((const __attribute__((address_space(1))) void*)g,
                                   (__attribute__((address_space(3))) void*)l, 16, 0, 0);
}

__global__ __launch_bounds__(256) void k_gemm(const u16* __restrict__ A, const u16* __restrict__ Bt,
                                              u16* __restrict__ C, float* __restrict__ es,
                                              float* __restrict__ ed, int ksteps, int K,
                                              int Dsplit, int Nreal, int ldC) {
  __shared__ __align__(16) u16 lA[2][128 * 32];
  __shared__ __align__(16) u16 lB[2][128 * 32];
  int t = threadIdx.x;
  int lane = t & 63, wv = t >> 6;

  // T1 XCD swizzle (bijective chunked, m204)
  int nwg = gridDim.x * gridDim.y;
  int h = blockIdx.y * gridDim.x + blockIdx.x;
  int q = nwg >> 3, r8 = nwg & 7;
  int xcd = h & 7, i8 = h >> 3;
  int ln = (xcd < r8 ? xcd * (q + 1) : r8 * (q + 1) + (xcd - r8) * q) + i8;
  int tn = (ln % gridDim.x) * 128, tm = (ln / gridDim.x) * 128;

  int wr = (wv >> 1) * 64, wc = (wv & 1) * 64;
  int rl = lane & 15, kl = (lane >> 4) * 8;
  int rdo = rl * 32 + (kl ^ (((rl >> 3) & 1) << 4));   // subtile-relative read offset

  f32x4 acc[4][4];
#pragma unroll
  for (int i = 0; i < 4; ++i)
#pragma unroll
    for (int j = 0; j < 4; ++j) acc[i][j] = (f32x4){0.f, 0.f, 0.f, 0.f};

  auto stage = [&](int buf, int ks) {
    int k0 = ks * 32;
#pragma unroll
    for (int r = 0; r < 2; ++r) {
      int chunk = r * 256 + t;
      int row = ((chunk >> 6) << 4) + ((chunk >> 2) & 15);          // subtile*16 + row_in
      int kb  = ((chunk & 3) << 3) ^ (((chunk >> 5) & 1) << 4);     // inverse XOR on source
      gl_lds16(A + (size_t)(tm + row) * K + k0 + kb, &lA[buf][chunk * 8]);
      gl_lds16(Bt + (size_t)(tn + row) * K + k0 + kb, &lB[buf][chunk * 8]);
    }
  };

  stage(0, 0);
  int cur = 0;
  for (int ks = 0; ks < ksteps; ++ks) {
    __syncthreads();                       // drains vmcnt(0): buf[cur] fully written
    if (ks + 1 < ksteps) stage(cur ^ 1, ks + 1);   // loads fly under the MFMAs below
    bf16x8 af[4], bfr[4];
#pragma unroll
    for (int i = 0; i < 4; ++i) {
      af[i]  = *(const bf16x8*)&lA[cur][(((wr + i * 16) >> 4) << 9) + rdo];
      bfr[i] = *(const bf16x8*)&lB[cur][(((wc + i * 16) >> 4) << 9) + rdo];
    }
#pragma unroll
    for (int i = 0; i < 4; ++i)
#pragma unroll
      for (int j = 0; j < 4; ++j)
        acc[i][j] = __builtin_amdgcn_mfma_f32_16x16x32_bf16(af[i], bfr[j], acc[i][j], 0, 0, 0);
    cur ^= 1;
  }
  int rq = (lane >> 4) * 4;
#pragma unroll
  for (int i = 0; i < 4; ++i) {
#pragma unroll
    for (int j = 0; j < 4; ++j) {
      int col = tn + wc + j * 16 + rl;
      if (col < Dsplit) {
#pragma unroll
        for (int q2 = 0; q2 < 4; ++q2) {
          int row = tm + wr + i * 16 + rq + q2;
          C[(size_t)row * ldC + col] = f2b(acc[i][j][q2]);
        }
      } else if (col < Nreal) {
        int cj = col - Dsplit;
        float* dst = (cj < 8) ? es : ed;
        int hh = cj & 7;
#pragma unroll
        for (int q2 = 0; q2 < 4; ++q2) {
          int row = tm + wr + i * 16 + rq + q2;
          dst[(size_t)row * 8 + hh] = acc[i][j][q2];
        }
      }
    }
  }
}

// ==== fused softmax-stats + aggregation (chunked in-LDS, no atomics) ====
// ex-production reads esrc directly from global (L1-hot broadcast) so ONE sync
// publishes both sm_ex and sm_src. Denominator accumulated for free inside the
// gather loop (value already loaded); redundant across the 25 threads per head.

// ---- layer-1: writes h1 (GEMM2 A-matrix) ----
__global__ __launch_bounds__(256) void k_agg1(const int* __restrict__ rs, const int* __restrict__ esrc,
    const u16* __restrict__ Hp, const float* __restrict__ es, const float* __restrict__ ed,
    const float* __restrict__ bias, u16* __restrict__ out) {
  __shared__ float sm_ex[CHK * 8];
  __shared__ int   sm_src[CHK];
  int n = blockIdx.x, t = threadIdx.x;
  int beg = rs[n], end = rs[n + 1];
  int c = t * 4;
  int h = t / 25;
  float edvh = ed[n * 8 + (t & 7)];    // hh for ex-production: i&7 == t&7 (256%8==0)
  float a0 = 0.f, a1 = 0.f, a2 = 0.f, a3 = 0.f, den = 0.f;
  for (int ch = beg; ch < end; ch += CHK) {
    int m = min(end, ch + CHK) - ch;
    if (t < m) sm_src[t] = esrc[ch + t];
    for (int i = t; i < m * 8; i += 256) {
      float xv = es[esrc[ch + (i >> 3)] * 8 + (i & 7)] + edvh;
      xv = xv > 0.f ? xv : NEG * xv;
      sm_ex[i] = __expf(xv);
    }
    __syncthreads();                   // publishes sm_ex + sm_src
    if (t < 200) {
      for (int j = 0; j < m; ++j) {
        float w = sm_ex[j * 8 + h];
        den += w;
        ushort4 u = *(const ushort4*)(Hp + (size_t)sm_src[j] * DIM + c);
        a0 += w * b2f(u.x); a1 += w * b2f(u.y); a2 += w * b2f(u.z); a3 += w * b2f(u.w);
      }
    }
    __syncthreads();                   // WAR before next chunk overwrite
  }
  if (t >= 200) return;
  float inv = 1.f / (den + 1e-16f);
  const float4 bb = *(const float4*)(bias + c);
  float v0 = a0 * inv + bb.x, v1 = a1 * inv + bb.y, v2 = a2 * inv + bb.z, v3 = a3 * inv + bb.w;
  v0 = v0 > 0.f ? v0 : __expf(v0) - 1.f;
  v1 = v1 > 0.f ? v1 : __expf(v1) - 1.f;
  v2 = v2 > 0.f ? v2 : __expf(v2) - 1.f;
  v3 = v3 > 0.f ? v3 : __expf(v3) - 1.f;
  ushort4 o;
  o.x = f2b(v0); o.y = f2b(v1); o.z = f2b(v2); o.w = f2b(v3);
  *(ushort4*)(out + (size_t)n * DIM + c) = o;
}

// ---- layer-2: fused stats + agg + resid + ELU + layer-3 skinny projections ----
__global__ __launch_bounds__(256) void k_agg2f(const int* __restrict__ rs, const int* __restrict__ esrc,
    const u16* __restrict__ Hp, const float* __restrict__ es, const float* __restrict__ ed,
    const float* __restrict__ bias, const u16* __restrict__ resid,
    const float* __restrict__ W3, const float* __restrict__ Wres2,
    const float* __restrict__ a3s, const float* __restrict__ a3d, const float* __restrict__ b3,
    const float* __restrict__ skp,
    float* __restrict__ H3p, float* __restrict__ base,
    float* __restrict__ es3, float* __restrict__ ed3) {
  __shared__ float sm_ex[CHK * 8];
  __shared__ int   sm_src[CHK];
  __shared__ float red[4][4];
  int n = blockIdx.x, t = threadIdx.x;
  int lane = t & 63, wv = t >> 6;
  int beg = rs[n], end = rs[n + 1];
  int c = t * 4;
  int h = t / 25;
  float edvh = ed[n * 8 + (t & 7)];
  float a0 = 0.f, a1 = 0.f, a2 = 0.f, a3 = 0.f, den = 0.f;
  for (int ch = beg; ch < end; ch += CHK) {
    int m = min(end, ch + CHK) - ch;
    if (t < m) sm_src[t] = esrc[ch + t];
    for (int i = t; i < m * 8; i += 256) {
      float xv = es[esrc[ch + (i >> 3)] * 8 + (i & 7)] + edvh;
      xv = xv > 0.f ? xv : NEG * xv;
      sm_ex[i] = __expf(xv);
    }
    __syncthreads();
    if (t < 200) {
      for (int j = 0; j < m; ++j) {
        float w = sm_ex[j * 8 + h];
        den += w;
        ushort4 u = *(const ushort4*)(Hp + (size_t)sm_src[j] * DIM2 + c);
        a0 += w * b2f(u.x); a1 += w * b2f(u.y); a2 += w * b2f(u.z); a3 += w * b2f(u.w);
      }
    }
    __syncthreads();
  }
  float p0 = 0.f, p1 = 0.f, r0 = 0.f, r1 = 0.f;
  if (t < 200) {
    float inv = 1.f / (den + 1e-16f);
    const float4 bb = *(const float4*)(bias + c);
    ushort4 rr = *(const ushort4*)(resid + (size_t)n * DIM2 + c);
    float v0 = a0 * inv + bb.x + b2f(rr.x);
    float v1 = a1 * inv + bb.y + b2f(rr.y);
    float v2 = a2 * inv + bb.z + b2f(rr.z);
    float v3 = a3 * inv + bb.w + b2f(rr.w);
    v0 = v0 > 0.f ? v0 : __expf(v0) - 1.f;
    v1 = v1 > 0.f ? v1 : __expf(v1) - 1.f;
    v2 = v2 > 0.f ? v2 : __expf(v2) - 1.f;
    v3 = v3 > 0.f ? v3 : __expf(v3) - 1.f;
    const float4 w3a = *(const float4*)(W3 + 2 * c);
    const float4 w3b = *(const float4*)(W3 + 2 * c + 4);
    const float4 wra = *(const float4*)(Wres2 + 2 * c);
    const float4 wrb = *(const float4*)(Wres2 + 2 * c + 4);
    p0 = v0 * w3a.x + v1 * w3a.z + v2 * w3b.x + v3 * w3b.z;
    p1 = v0 * w3a.y + v1 * w3a.w + v2 * w3b.y + v3 * w3b.w;
    r0 = v0 * wra.x + v1 * wra.z + v2 * wrb.x + v3 * wrb.z;
    r1 = v0 * wra.y + v1 * wra.w + v2 * wrb.y + v3 * wrb.w;
  }
#pragma unroll
  for (int off = 32; off; off >>= 1) {
    p0 += __shfl_down(p0, off); p1 += __shfl_down(p1, off);
    r0 += __shfl_down(r0, off); r1 += __shfl_down(r1, off);
  }
  if (!lane) { red[wv][0] = p0; red[wv][1] = p1; red[wv][2] = r0; red[wv][3] = r1; }
  __syncthreads();
  if (!t) {
    float P0 = red[0][0] + red[1][0] + red[2][0] + red[3][0];
    float P1 = red[0][1] + red[1][1] + red[2][1] + red[3][1];
    float R0 = red[0][2] + red[1][2] + red[2][2] + red[3][2];
    float R1 = red[0][3] + red[1][3] + red[2][3] + red[3][3];
    H3p[2 * n] = P0; H3p[2 * n + 1] = P1;
    es3[n] = P0 * a3s[0] + P1 * a3s[1];
    ed3[n] = P0 * a3d[0] + P1 * a3d[1];
    base[2 * n]     = R0 + skp[2 * n]     + b3[0];
    base[2 * n + 1] = R1 + skp[2 * n + 1] + b3[1];
  }
}

// ---------------- layer 3 softmax+aggregate (1 head, 2 ch) -> final logits ----------------
__global__ void k_l3agg(const int* __restrict__ rs, const int* __restrict__ esrc,
                        const float* __restrict__ H3p, const float* __restrict__ base,
                        const float* __restrict__ es3, const float* __restrict__ ed3,
                        float* __restrict__ out) {
  int n = blockIdx.x * 256 + threadIdx.x;
  if (n >= NN) return;
  int beg = rs[n], end = rs[n + 1];
  float edv = ed3[n];
  float den = 0.f, a0 = 0.f, a1 = 0.f;
  for (int j = beg; j < end; ++j) {
    int s = esrc[j];
    float e = es3[s] + edv;
    e = e > 0.f ? e : NEG * e;
    float exv = __expf(e);
    den += exv;
    a0 += exv * H3p[2 * s];
    a1 += exv * H3p[2 * s + 1];
  }
  float inv = 1.f / (den + 1e-16f);
  out[2 * n]     = base[2 * n]     + a0 * inv;
  out[2 * n + 1] = base[2 * n + 1] + a1 * inv;
}

extern "C" void kernel_launch(void* const* d_in, const int* in_sizes, int n_in,
                              void* d_out, int out_size, void* d_ws, size_t ws_size,
                              hipStream_t stream) {
  (void)in_sizes; (void)n_in; (void)out_size; (void)ws_size;
  const float* x    = (const float*)d_in[0];
  const int*   ei   = (const int*)d_in[1];
  const float* W1   = (const float*)d_in[2];
  const float* a1s  = (const float*)d_in[3];
  const float* a1d  = (const float*)d_in[4];
  const float* b1   = (const float*)d_in[5];
  const float* W2   = (const float*)d_in[6];
  const float* a2s  = (const float*)d_in[7];
  const float* a2d  = (const float*)d_in[8];
  const float* b2   = (const float*)d_in[9];
  const float* W3   = (const float*)d_in[10];
  const float* a3s  = (const float*)d_in[11];
  const float* a3d  = (const float*)d_in[12];
  const float* b3   = (const float*)d_in[13];
  const float* Wr1  = (const float*)d_in[14];
  const float* Wr2  = (const float*)d_in[15];
  const float* Wsk  = (const float*)d_in[16];
  float* out = (float*)d_out;

  // ---- workspace (~250 MB) ----
  char* w = (char*)d_ws;
  size_t off = 0;
  auto alloc = [&](size_t bytes) { void* p = w + off; off += (bytes + 255) & ~(size_t)255; return p; };
  int* cnt   = (int*)alloc((size_t)NN * 4);
  int* cur   = (int*)alloc((size_t)NN * 4);
  int* rs    = (int*)alloc((size_t)(NN + 1) * 4);
  int* bs    = (int*)alloc(256 * 4);
  int* esrc  = (int*)alloc((size_t)ETOT * 4);
  float* es  = (float*)alloc((size_t)MPAD * HEADS * 4);
  float* ed  = (float*)alloc((size_t)MPAD * HEADS * 4);
  u16* W1t   = (u16*)alloc((size_t)NP1 * KP1 * 2);
  u16* W2t   = (u16*)alloc((size_t)NP2 * DIM * 2);
  float* H3p = (float*)alloc((size_t)NN * 2 * 4);
  float* base= (float*)alloc((size_t)NN * 2 * 4);
  float* es3 = (float*)alloc((size_t)NN * 4);
  float* ed3 = (float*)alloc((size_t)NN * 4);
  float* skp = (float*)alloc((size_t)NN * 2 * 4);
  u16* bufB  = (u16*)alloc((size_t)MPAD * DIM * 2);    // h1bf (GEMM2 A)
  u16* bufA  = (u16*)alloc((size_t)MPAD * DIM2 * 2);   // H1p, later G2 (fused proj|resid)
  u16* H1p   = bufA;
  u16* G2    = bufA;
  u16* A1    = bufA + (size_t)MPAD * DIM;              // alias upper half of bufA (dead before G2)

  const int nb = (NN + 255) / 256;        // 196
  const int ge = (ETOT + 255) / 256;      // 977

  // fused prep (includes zeroing cnt/cur for the CSR build)
  k_prep<<<PR_Z, 256, 0, stream>>>(x, W1, a1s, a1d, W2, Wr1, a2s, a2d, Wsk,
                                   A1, W1t, W2t, skp, cnt, cur);

  // CSR build
  k_count<<<ge, 256, 0, stream>>>(ei, cnt);
  k_bsum <<<nb, 256, 0, stream>>>(cnt, bs);
  k_top  <<<1, 256, 0, stream>>>(bs, rs, nb);
  k_scan <<<nb, 256, 0, stream>>>(cnt, bs, rs);
  k_fill <<<ge, 256, 0, stream>>>(ei, rs, cur, esrc);

  // layer 1 (GEMM also emits es/ed via fused columns 800-815)
  k_gemm<<<dim3(NP1 / 128, MPAD / 128), 256, 0, stream>>>(A1, W1t, H1p, es, ed,
                                                          KP1 / 32, KP1, DIM, DIM + 16, DIM);
  k_agg1<<<NN, 256, 0, stream>>>(rs, esrc, H1p, es, ed, b1, bufB);

  // layer 2 (W2|Wres1 fused GEMM; es/ed via fused columns 1600-1615)
  k_gemm<<<dim3(NP2 / 128, MPAD / 128), 256, 0, stream>>>(bufB, W2t, G2, es, ed,
                                                          DIM / 32, DIM, DIM2, DIM2 + 16, DIM2);
  k_agg2f<<<NN, 256, 0, stream>>>(rs, esrc, G2, es, ed, b2, G2 + DIM,
                                  W3, Wr2, a3s, a3d, b3, skp, H3p, base, es3, ed3);

  // layer 3 softmax-aggregate
  k_l3agg<<<nb, 256, 0, stream>>>(rs, esrc, H3p, base, es3, ed3, out);
}

// Round 14
// 458.973 us; speedup vs baseline: 1.3019x; 1.0454x over previous
//
#include <hip/hip_runtime.h>

#define NN     50000
#define NE     200000
#define ETOT   250000   // NE + NN self-loops
#define FIN    165
#define KP1    192      // FIN padded to mult of 32
#define HEADS  8
#define CH     100
#define DIM    800      // 8*100
#define MPAD   50048    // 391*128
#define NP1    896      // 7*128  (pad of 816: 800 data + 16 es/ed)
#define DIM2   1600     // W2|Wres1 fused output
#define NP2    1664     // 13*128 (pad of 1616: 1600 data + 16 es/ed)
#define NEG    0.2f
#define CHK    64       // agg softmax chunk (LDS ex buffer = CHK*8 floats)

typedef unsigned short u16;
typedef unsigned int   u32;
typedef __bf16 bf16x8 __attribute__((ext_vector_type(8)));
typedef float  f32x4  __attribute__((ext_vector_type(4)));

__device__ __forceinline__ u16 f2b(float f) {
  u32 u = __float_as_uint(f);
  u = (u + 0x7FFFu + ((u >> 16) & 1u)) >> 16;   // RNE
  return (u16)u;
}
__device__ __forceinline__ float b2f(u16 u) { return __uint_as_float(((u32)u) << 16); }

// ---------------- CSR build (dst -> list of src), reused by all 3 layers ----------------
__global__ void k_count(const int* __restrict__ ei, int* __restrict__ cnt) {
  int e = blockIdx.x * 256 + threadIdx.x;
  if (e >= ETOT) return;
  int d = (e < NE) ? ei[NE + e] : (e - NE);
  atomicAdd(&cnt[d], 1);
}
__global__ void k_bsum(const int* __restrict__ cnt, int* __restrict__ bs) {
  __shared__ int sm[256];
  int i = blockIdx.x * 256 + threadIdx.x;
  sm[threadIdx.x] = (i < NN) ? cnt[i] : 0;
  __syncthreads();
  for (int off = 128; off; off >>= 1) {
    if (threadIdx.x < off) sm[threadIdx.x] += sm[threadIdx.x + off];
    __syncthreads();
  }
  if (!threadIdx.x) bs[blockIdx.x] = sm[0];
}
__global__ void k_top(int* __restrict__ bs, int* __restrict__ rs, int nb) {
  __shared__ int sm[256];
  int t = threadIdx.x;
  int v = (t < nb) ? bs[t] : 0;
  sm[t] = v; __syncthreads();
  for (int off = 1; off < 256; off <<= 1) {
    int add = (t >= off) ? sm[t - off] : 0;
    __syncthreads();
    sm[t] += add;
    __syncthreads();
  }
  if (t < nb) bs[t] = sm[t] - v;   // exclusive block offsets
  if (!t) rs[NN] = ETOT;
}
__global__ void k_scan(const int* __restrict__ cnt, const int* __restrict__ bs, int* __restrict__ rs) {
  __shared__ int sm[256];
  int t = threadIdx.x, i = blockIdx.x * 256 + t;
  int v = (i < NN) ? cnt[i] : 0;
  sm[t] = v; __syncthreads();
  for (int off = 1; off < 256; off <<= 1) {
    int add = (t >= off) ? sm[t - off] : 0;
    __syncthreads();
    sm[t] += add;
    __syncthreads();
  }
  if (i < NN) rs[i] = bs[blockIdx.x] + sm[t] - v;
}
__global__ void k_fill(const int* __restrict__ ei, const int* __restrict__ rs,
                       int* __restrict__ cur, int* __restrict__ esrc) {
  int e = blockIdx.x * 256 + threadIdx.x;
  if (e >= ETOT) return;
  int s, d;
  if (e < NE) { s = ei[e]; d = ei[NE + e]; } else { s = d = e - NE; }
  int pos = atomicAdd(&cur[d], 1);
  esrc[rs[d] + pos] = s;
}

// ==== fused prep: converts + fused-attention weight cols + x@Wskip + zero cnt/cur ====
#define PR_X   9384    // MPAD*KP1/4/256
#define PR_W1  10056   // + NP1*KP1/256 (672)
#define PR_WA1 10068   // + 16*KP1/256 (12)
#define PR_W2  15268   // + NP2*DIM/256 (5200)
#define PR_WA2 15318   // + 16*DIM/256 (50)
#define PR_L3X 27818   // + (NN+3)/4 (12500)
#define PR_Z   28209   // + ceil(2*NN/256) (391)

__device__ __forceinline__ void d_wa(int idx, const float* W, const float* as,
                                     const float* ad, u16* Wt, int Kin, int Kpad, int Dsp) {
  int j = idx / Kpad, k = idx - j * Kpad;
  int h = j & 7;
  const float* a = ((j < 8) ? as : ad) + h * CH;
  float s = 0.f;
  if (k < Kin) {
    const float* wr = W + (size_t)k * DIM + h * CH;
    for (int c = 0; c < CH; ++c) s += wr[c] * a[c];
  }
  Wt[(size_t)(Dsp + j) * Kpad + k] = f2b(s);
}

__global__ __launch_bounds__(256) void k_prep(const float* __restrict__ x,
    const float* __restrict__ W1, const float* __restrict__ a1s, const float* __restrict__ a1d,
    const float* __restrict__ W2, const float* __restrict__ Wr1,
    const float* __restrict__ a2s, const float* __restrict__ a2d,
    const float* __restrict__ Wsk,
    u16* __restrict__ A1, u16* __restrict__ W1t, u16* __restrict__ W2t,
    float* __restrict__ skp, int* __restrict__ cnt, int* __restrict__ cur) {
  int b = blockIdx.x, t = threadIdx.x;
  if (b < PR_X) {                      // x -> bf16 padded [MPAD][KP1], 4 elems/thread
    int idx4 = b * 256 + t;
    int r = idx4 / 48;                 // KP1/4 = 48
    int kq = (idx4 - r * 48) * 4;
    ushort4 o = (ushort4){0, 0, 0, 0};
    if (r < NN) {
      const float* xr = x + (size_t)r * FIN;
      float v0 = (kq + 0 < FIN) ? xr[kq + 0] : 0.f;
      float v1 = (kq + 1 < FIN) ? xr[kq + 1] : 0.f;
      float v2 = (kq + 2 < FIN) ? xr[kq + 2] : 0.f;
      float v3 = (kq + 3 < FIN) ? xr[kq + 3] : 0.f;
      o.x = f2b(v0); o.y = f2b(v1); o.z = f2b(v2); o.w = f2b(v3);
    }
    *(ushort4*)(A1 + (size_t)r * KP1 + kq) = o;
  } else if (b < PR_W1) {              // W1^T bf16 [NP1][KP1] (zero pad rows)
    int idx = (b - PR_X) * 256 + t;
    int j = idx / KP1, k = idx - j * KP1;
    float v = (j < DIM && k < FIN) ? W1[k * DIM + j] : 0.f;
    W1t[idx] = f2b(v);
  } else if (b < PR_WA1) {             // fused es/ed cols for layer 1
    int idx = (b - PR_W1) * 256 + t;
    d_wa(idx, W1, a1s, a1d, W1t, FIN, KP1, DIM);
  } else if (b < PR_W2) {              // [W2|Wres1]^T bf16 [NP2][DIM]
    int idx = (b - PR_WA1) * 256 + t;
    int j = idx / DIM, k = idx - j * DIM;
    float v = 0.f;
    if (j < DIM) v = W2[k * DIM + j];
    else if (j < 2 * DIM) v = Wr1[k * DIM + (j - DIM)];
    W2t[idx] = f2b(v);
  } else if (b < PR_WA2) {             // fused es/ed cols for layer 2
    int idx = (b - PR_W2) * 256 + t;
    d_wa(idx, W2, a2s, a2d, W2t, DIM, DIM, DIM2);
  } else if (b < PR_L3X) {             // x @ Wskip (one wave per node)
    int wv = t >> 6, lane = t & 63;
    int n = (b - PR_WA2) * 4 + wv;
    if (n >= NN) return;
    float s0 = 0.f, s1 = 0.f;
    const float* xr = x + (size_t)n * FIN;
    for (int c = lane; c < FIN; c += 64) {
      float v = xr[c];
      s0 += v * Wsk[2 * c]; s1 += v * Wsk[2 * c + 1];
    }
#pragma unroll
    for (int off = 32; off; off >>= 1) {
      s0 += __shfl_down(s0, off); s1 += __shfl_down(s1, off);
    }
    if (!lane) { skp[2 * n] = s0; skp[2 * n + 1] = s1; }
  } else {                             // zero cnt + cur
    int i = (b - PR_L3X) * 256 + t;
    if (i < NN) cnt[i] = 0;
    else if (i < 2 * NN) cur[i - NN] = 0;
  }
}

// ---------------- bf16 MFMA GEMM: 128^2 tile, BK=32, 2-phase dbuf ----------------
// LDS layout (R12-proven, 0 bank conflicts): 8 subtiles of [16 rows][32 k];
// within a subtile, k-block stored at col = k ^ ((row_in>>3)&1)*16.
// gload_lds dest LINEAR; GLOBAL source inverse-permuted; ds_read same XOR.
// __launch_bounds__(256,4): cap total regs/wave at 128 (68 arch + 64 acc = 132
// was the 3-wave/SIMD occupancy cliff; R13 counters: everything idle at 31% occ).
__device__ __forceinline__ void gl_lds16(const u16* g, u16* l) {
  __builtin_amdgcn_global_load_lds((const __attribute__((address_space(1))) void*)g,
                                   (__attribute__((address_space(3))) void*)l, 16, 0, 0);
}

__global__ __launch_bounds__(256, 4) void k_gemm(const u16* __restrict__ A, const u16* __restrict__ Bt,
                                              u16* __restrict__ C, float* __restrict__ es,
                                              float* __restrict__ ed, int ksteps, int K,
                                              int Dsplit, int Nreal, int ldC) {
  __shared__ __align__(16) u16 lA[2][128 * 32];
  __shared__ __align__(16) u16 lB[2][128 * 32];
  int t = threadIdx.x;
  int lane = t & 63, wv = t >> 6;

  // T1 XCD swizzle (bijective chunked, m204)
  int nwg = gridDim.x * gridDim.y;
  int h = blockIdx.y * gridDim.x + blockIdx.x;
  int q = nwg >> 3, r8 = nwg & 7;
  int xcd = h & 7, i8 = h >> 3;
  int ln = (xcd < r8 ? xcd * (q + 1) : r8 * (q + 1) + (xcd - r8) * q) + i8;
  int tn = (ln % gridDim.x) * 128, tm = (ln / gridDim.x) * 128;

  int wr = (wv >> 1) * 64, wc = (wv & 1) * 64;
  int rl = lane & 15, kl = (lane >> 4) * 8;
  int rdo = rl * 32 + (kl ^ (((rl >> 3) & 1) << 4));   // subtile-relative read offset

  f32x4 acc[4][4];
#pragma unroll
  for (int i = 0; i < 4; ++i)
#pragma unroll
    for (int j = 0; j < 4; ++j) acc[i][j] = (f32x4){0.f, 0.f, 0.f, 0.f};

  auto stage = [&](int buf, int ks) {
    int k0 = ks * 32;
#pragma unroll
    for (int r = 0; r < 2; ++r) {
      int chunk = r * 256 + t;
      int row = ((chunk >> 6) << 4) + ((chunk >> 2) & 15);          // subtile*16 + row_in
      int kb  = ((chunk & 3) << 3) ^ (((chunk >> 5) & 1) << 4);     // inverse XOR on source
      gl_lds16(A + (size_t)(tm + row) * K + k0 + kb, &lA[buf][chunk * 8]);
      gl_lds16(Bt + (size_t)(tn + row) * K + k0 + kb, &lB[buf][chunk * 8]);
    }
  };

  stage(0, 0);
  int cur = 0;
  for (int ks = 0; ks < ksteps; ++ks) {
    __syncthreads();                       // drains vmcnt(0): buf[cur] fully written
    if (ks + 1 < ksteps) stage(cur ^ 1, ks + 1);   // loads fly under the MFMAs below
    bf16x8 af[4], bfr[4];
#pragma unroll
    for (int i = 0; i < 4; ++i) {
      af[i]  = *(const bf16x8*)&lA[cur][(((wr + i * 16) >> 4) << 9) + rdo];
      bfr[i] = *(const bf16x8*)&lB[cur][(((wc + i * 16) >> 4) << 9) + rdo];
    }
#pragma unroll
    for (int i = 0; i < 4; ++i)
#pragma unroll
      for (int j = 0; j < 4; ++j)
        acc[i][j] = __builtin_amdgcn_mfma_f32_16x16x32_bf16(af[i], bfr[j], acc[i][j], 0, 0, 0);
    cur ^= 1;
  }
  int rq = (lane >> 4) * 4;
#pragma unroll
  for (int i = 0; i < 4; ++i) {
#pragma unroll
    for (int j = 0; j < 4; ++j) {
      int col = tn + wc + j * 16 + rl;
      if (col < Dsplit) {
#pragma unroll
        for (int q2 = 0; q2 < 4; ++q2) {
          int row = tm + wr + i * 16 + rq + q2;
          C[(size_t)row * ldC + col] = f2b(acc[i][j][q2]);
        }
      } else if (col < Nreal) {
        int cj = col - Dsplit;
        float* dst = (cj < 8) ? es : ed;
        int hh = cj & 7;
#pragma unroll
        for (int q2 = 0; q2 < 4; ++q2) {
          int row = tm + wr + i * 16 + rq + q2;
          dst[(size_t)row * 8 + hh] = acc[i][j][q2];
        }
      }
    }
  }
}

// ==== fused softmax-stats + aggregation (chunked in-LDS, no atomics) ====
// Trailing WAR-barrier skipped on the LAST chunk (avg degree 5 -> ~1 chunk/block).

// ---- layer-1: writes h1 (GEMM2 A-matrix) ----
__global__ __launch_bounds__(256) void k_agg1(const int* __restrict__ rs, const int* __restrict__ esrc,
    const u16* __restrict__ Hp, const float* __restrict__ es, const float* __restrict__ ed,
    const float* __restrict__ bias, u16* __restrict__ out) {
  __shared__ float sm_ex[CHK * 8];
  __shared__ int   sm_src[CHK];
  int n = blockIdx.x, t = threadIdx.x;
  int beg = rs[n], end = rs[n + 1];
  int c = t * 4;
  int h = t / 25;
  float edvh = ed[n * 8 + (t & 7)];    // hh for ex-production: i&7 == t&7 (256%8==0)
  float a0 = 0.f, a1 = 0.f, a2 = 0.f, a3 = 0.f, den = 0.f;
  for (int ch = beg; ch < end; ch += CHK) {
    int m = min(end, ch + CHK) - ch;
    if (t < m) sm_src[t] = esrc[ch + t];
    for (int i = t; i < m * 8; i += 256) {
      float xv = es[esrc[ch + (i >> 3)] * 8 + (i & 7)] + edvh;
      xv = xv > 0.f ? xv : NEG * xv;
      sm_ex[i] = __expf(xv);
    }
    __syncthreads();                   // publishes sm_ex + sm_src
    if (t < 200) {
      for (int j = 0; j < m; ++j) {
        float w = sm_ex[j * 8 + h];
        den += w;
        ushort4 u = *(const ushort4*)(Hp + (size_t)sm_src[j] * DIM + c);
        a0 += w * b2f(u.x); a1 += w * b2f(u.y); a2 += w * b2f(u.z); a3 += w * b2f(u.w);
      }
    }
    if (ch + CHK < end) __syncthreads();   // WAR only if another chunk follows
  }
  if (t >= 200) return;
  float inv = 1.f / (den + 1e-16f);
  const float4 bb = *(const float4*)(bias + c);
  float v0 = a0 * inv + bb.x, v1 = a1 * inv + bb.y, v2 = a2 * inv + bb.z, v3 = a3 * inv + bb.w;
  v0 = v0 > 0.f ? v0 : __expf(v0) - 1.f;
  v1 = v1 > 0.f ? v1 : __expf(v1) - 1.f;
  v2 = v2 > 0.f ? v2 : __expf(v2) - 1.f;
  v3 = v3 > 0.f ? v3 : __expf(v3) - 1.f;
  ushort4 o;
  o.x = f2b(v0); o.y = f2b(v1); o.z = f2b(v2); o.w = f2b(v3);
  *(ushort4*)(out + (size_t)n * DIM + c) = o;
}

// ---- layer-2: fused stats + agg + resid + ELU + layer-3 skinny projections ----
__global__ __launch_bounds__(256) void k_agg2f(const int* __restrict__ rs, const int* __restrict__ esrc,
    const u16* __restrict__ Hp, const float* __restrict__ es, const float* __restrict__ ed,
    const float* __restrict__ bias, const u16* __restrict__ resid,
    const float* __restrict__ W3, const float* __restrict__ Wres2,
    const float* __restrict__ a3s, const float* __restrict__ a3d, const float* __restrict__ b3,
    const float* __restrict__ skp,
    float* __restrict__ H3p, float* __restrict__ base,
    float* __restrict__ es3, float* __restrict__ ed3) {
  __shared__ float sm_ex[CHK * 8];
  __shared__ int   sm_src[CHK];
  __shared__ float red[4][4];
  int n = blockIdx.x, t = threadIdx.x;
  int lane = t & 63, wv = t >> 6;
  int beg = rs[n], end = rs[n + 1];
  int c = t * 4;
  int h = t / 25;
  float edvh = ed[n * 8 + (t & 7)];
  float a0 = 0.f, a1 = 0.f, a2 = 0.f, a3 = 0.f, den = 0.f;
  for (int ch = beg; ch < end; ch += CHK) {
    int m = min(end, ch + CHK) - ch;
    if (t < m) sm_src[t] = esrc[ch + t];
    for (int i = t; i < m * 8; i += 256) {
      float xv = es[esrc[ch + (i >> 3)] * 8 + (i & 7)] + edvh;
      xv = xv > 0.f ? xv : NEG * xv;
      sm_ex[i] = __expf(xv);
    }
    __syncthreads();
    if (t < 200) {
      for (int j = 0; j < m; ++j) {
        float w = sm_ex[j * 8 + h];
        den += w;
        ushort4 u = *(const ushort4*)(Hp + (size_t)sm_src[j] * DIM2 + c);
        a0 += w * b2f(u.x); a1 += w * b2f(u.y); a2 += w * b2f(u.z); a3 += w * b2f(u.w);
      }
    }
    if (ch + CHK < end) __syncthreads();
  }
  float p0 = 0.f, p1 = 0.f, r0 = 0.f, r1 = 0.f;
  if (t < 200) {
    float inv = 1.f / (den + 1e-16f);
    const float4 bb = *(const float4*)(bias + c);
    ushort4 rr = *(const ushort4*)(resid + (size_t)n * DIM2 + c);
    float v0 = a0 * inv + bb.x + b2f(rr.x);
    float v1 = a1 * inv + bb.y + b2f(rr.y);
    float v2 = a2 * inv + bb.z + b2f(rr.z);
    float v3 = a3 * inv + bb.w + b2f(rr.w);
    v0 = v0 > 0.f ? v0 : __expf(v0) - 1.f;
    v1 = v1 > 0.f ? v1 : __expf(v1) - 1.f;
    v2 = v2 > 0.f ? v2 : __expf(v2) - 1.f;
    v3 = v3 > 0.f ? v3 : __expf(v3) - 1.f;
    const float4 w3a = *(const float4*)(W3 + 2 * c);
    const float4 w3b = *(const float4*)(W3 + 2 * c + 4);
    const float4 wra = *(const float4*)(Wres2 + 2 * c);
    const float4 wrb = *(const float4*)(Wres2 + 2 * c + 4);
    p0 = v0 * w3a.x + v1 * w3a.z + v2 * w3b.x + v3 * w3b.z;
    p1 = v0 * w3a.y + v1 * w3a.w + v2 * w3b.y + v3 * w3b.w;
    r0 = v0 * wra.x + v1 * wra.z + v2 * wrb.x + v3 * wrb.z;
    r1 = v0 * wra.y + v1 * wra.w + v2 * wrb.y + v3 * wrb.w;
  }
#pragma unroll
  for (int off = 32; off; off >>= 1) {
    p0 += __shfl_down(p0, off); p1 += __shfl_down(p1, off);
    r0 += __shfl_down(r0, off); r1 += __shfl_down(r1, off);
  }
  if (!lane) { red[wv][0] = p0; red[wv][1] = p1; red[wv][2] = r0; red[wv][3] = r1; }
  __syncthreads();
  if (!t) {
    float P0 = red[0][0] + red[1][0] + red[2][0] + red[3][0];
    float P1 = red[0][1] + red[1][1] + red[2][1] + red[3][1];
    float R0 = red[0][2] + red[1][2] + red[2][2] + red[3][2];
    float R1 = red[0][3] + red[1][3] + red[2][3] + red[3][3];
    H3p[2 * n] = P0; H3p[2 * n + 1] = P1;
    es3[n] = P0 * a3s[0] + P1 * a3s[1];
    ed3[n] = P0 * a3d[0] + P1 * a3d[1];
    base[2 * n]     = R0 + skp[2 * n]     + b3[0];
    base[2 * n + 1] = R1 + skp[2 * n + 1] + b3[1];
  }
}

// ---------------- layer 3 softmax+aggregate (1 head, 2 ch) -> final logits ----------------
__global__ void k_l3agg(const int* __restrict__ rs, const int* __restrict__ esrc,
                        const float* __restrict__ H3p, const float* __restrict__ base,
                        const float* __restrict__ es3, const float* __restrict__ ed3,
                        float* __restrict__ out) {
  int n = blockIdx.x * 256 + threadIdx.x;
  if (n >= NN) return;
  int beg = rs[n], end = rs[n + 1];
  float edv = ed3[n];
  float den = 0.f, a0 = 0.f, a1 = 0.f;
  for (int j = beg; j < end; ++j) {
    int s = esrc[j];
    float e = es3[s] + edv;
    e = e > 0.f ? e : NEG * e;
    float exv = __expf(e);
    den += exv;
    a0 += exv * H3p[2 * s];
    a1 += exv * H3p[2 * s + 1];
  }
  float inv = 1.f / (den + 1e-16f);
  out[2 * n]     = base[2 * n]     + a0 * inv;
  out[2 * n + 1] = base[2 * n + 1] + a1 * inv;
}

extern "C" void kernel_launch(void* const* d_in, const int* in_sizes, int n_in,
                              void* d_out, int out_size, void* d_ws, size_t ws_size,
                              hipStream_t stream) {
  (void)in_sizes; (void)n_in; (void)out_size; (void)ws_size;
  const float* x    = (const float*)d_in[0];
  const int*   ei   = (const int*)d_in[1];
  const float* W1   = (const float*)d_in[2];
  const float* a1s  = (const float*)d_in[3];
  const float* a1d  = (const float*)d_in[4];
  const float* b1   = (const float*)d_in[5];
  const float* W2   = (const float*)d_in[6];
  const float* a2s  = (const float*)d_in[7];
  const float* a2d  = (const float*)d_in[8];
  const float* b2   = (const float*)d_in[9];
  const float* W3   = (const float*)d_in[10];
  const float* a3s  = (const float*)d_in[11];
  const float* a3d  = (const float*)d_in[12];
  const float* b3   = (const float*)d_in[13];
  const float* Wr1  = (const float*)d_in[14];
  const float* Wr2  = (const float*)d_in[15];
  const float* Wsk  = (const float*)d_in[16];
  float* out = (float*)d_out;

  // ---- workspace (~250 MB) ----
  char* w = (char*)d_ws;
  size_t off = 0;
  auto alloc = [&](size_t bytes) { void* p = w + off; off += (bytes + 255) & ~(size_t)255; return p; };
  int* cnt   = (int*)alloc((size_t)NN * 4);
  int* cur   = (int*)alloc((size_t)NN * 4);
  int* rs    = (int*)alloc((size_t)(NN + 1) * 4);
  int* bs    = (int*)alloc(256 * 4);
  int* esrc  = (int*)alloc((size_t)ETOT * 4);
  float* es  = (float*)alloc((size_t)MPAD * HEADS * 4);
  float* ed  = (float*)alloc((size_t)MPAD * HEADS * 4);
  u16* W1t   = (u16*)alloc((size_t)NP1 * KP1 * 2);
  u16* W2t   = (u16*)alloc((size_t)NP2 * DIM * 2);
  float* H3p = (float*)alloc((size_t)NN * 2 * 4);
  float* base= (float*)alloc((size_t)NN * 2 * 4);
  float* es3 = (float*)alloc((size_t)NN * 4);
  float* ed3 = (float*)alloc((size_t)NN * 4);
  float* skp = (float*)alloc((size_t)NN * 2 * 4);
  u16* bufB  = (u16*)alloc((size_t)MPAD * DIM * 2);    // h1bf (GEMM2 A)
  u16* bufA  = (u16*)alloc((size_t)MPAD * DIM2 * 2);   // H1p, later G2 (fused proj|resid)
  u16* H1p   = bufA;
  u16* G2    = bufA;
  u16* A1    = bufA + (size_t)MPAD * DIM;              // alias upper half of bufA (dead before G2)

  const int nb = (NN + 255) / 256;        // 196
  const int ge = (ETOT + 255) / 256;      // 977

  // fused prep (includes zeroing cnt/cur for the CSR build)
  k_prep<<<PR_Z, 256, 0, stream>>>(x, W1, a1s, a1d, W2, Wr1, a2s, a2d, Wsk,
                                   A1, W1t, W2t, skp, cnt, cur);

  // CSR build
  k_count<<<ge, 256, 0, stream>>>(ei, cnt);
  k_bsum <<<nb, 256, 0, stream>>>(cnt, bs);
  k_top  <<<1, 256, 0, stream>>>(bs, rs, nb);
  k_scan <<<nb, 256, 0, stream>>>(cnt, bs, rs);
  k_fill <<<ge, 256, 0, stream>>>(ei, rs, cur, esrc);

  // layer 1 (GEMM also emits es/ed via fused columns 800-815)
  k_gemm<<<dim3(NP1 / 128, MPAD / 128), 256, 0, stream>>>(A1, W1t, H1p, es, ed,
                                                          KP1 / 32, KP1, DIM, DIM + 16, DIM);
  k_agg1<<<NN, 256, 0, stream>>>(rs, esrc, H1p, es, ed, b1, bufB);

  // layer 2 (W2|Wres1 fused GEMM; es/ed via fused columns 1600-1615)
  k_gemm<<<dim3(NP2 / 128, MPAD / 128), 256, 0, stream>>>(bufB, W2t, G2, es, ed,
                                                          DIM / 32, DIM, DIM2, DIM2 + 16, DIM2);
  k_agg2f<<<NN, 256, 0, stream>>>(rs, esrc, G2, es, ed, b2, G2 + DIM,
                                  W3, Wr2, a3s, a3d, b3, skp, H3p, base, es3, ed3);

  // layer 3 softmax-aggregate
  k_l3agg<<<nb, 256, 0, stream>>>(rs, esrc, H3p, base, es3, ed3, out);
}